// Round 4
// baseline (456.300 us; speedup 1.0000x reference)
//
#include <hip/hip_runtime.h>

typedef unsigned short u16;
typedef __attribute__((ext_vector_type(8))) short bf16x8;
typedef __attribute__((ext_vector_type(4))) float f32x4;

#define NN    10000
#define EE    160000
#define ET    170000      // EE + NN self loops
#define FIN   2000
#define MPAD  10112       // 79*128
#define K1PAD 2048
#define NH    1280        // heads*channels
#define HEADS 10
#define NT    10          // N tiles (1280/128) == heads
#define NWG   790         // 79*10 gemm workgroups
#define AGG_SLOTS 3126    // 2500 primary + 313 (head8) + 313 (head9)

__device__ __forceinline__ u16 f32_to_bf16(float f) {
    unsigned u = __float_as_uint(f);
    unsigned r = (u + 0x7fffu + ((u >> 16) & 1u)) >> 16;
    return (u16)r;
}
__device__ __forceinline__ float bf16lo(unsigned pv) { return __uint_as_float(pv << 16); }
__device__ __forceinline__ float bf16hi(unsigned pv) { return __uint_as_float(pv & 0xffff0000u); }

__device__ __forceinline__ void gload16(const u16* g, u16* l) {
    __builtin_amdgcn_global_load_lds(
        (const __attribute__((address_space(1))) void*)g,
        (__attribute__((address_space(3))) void*)l, 16, 0, 0);
}

// ---------------- conversion kernels ----------------

__global__ __launch_bounds__(256) void k_conv_x(const float* __restrict__ x,
                                                uint2* __restrict__ A1) {
    const int total = MPAD * (K1PAD / 4);
    for (int idx = blockIdx.x * 256 + threadIdx.x; idx < total; idx += gridDim.x * 256) {
        int r = idx >> 9;
        int c = (idx & 511) << 2;
        float4 v = make_float4(0.f, 0.f, 0.f, 0.f);
        if (r < NN && c < FIN) v = *(const float4*)(x + (size_t)r * FIN + c);
        uint2 p;
        p.x = (unsigned)f32_to_bf16(v.x) | ((unsigned)f32_to_bf16(v.y) << 16);
        p.y = (unsigned)f32_to_bf16(v.z) | ((unsigned)f32_to_bf16(v.w) << 16);
        A1[idx] = p;
    }
}

__global__ __launch_bounds__(256) void k_convT(const float* __restrict__ W,
                                               u16* __restrict__ Bt,
                                               int K, int Nn, int Kpad) {
    __shared__ float tile[32][33];
    int k0 = blockIdx.x * 32, n0 = blockIdx.y * 32;
    int tx = threadIdx.x, ty = threadIdx.y;   // (32,8)
    #pragma unroll
    for (int i = 0; i < 32; i += 8) {
        int k = k0 + ty + i;
        tile[ty + i][tx] = (k < K) ? W[(size_t)k * Nn + n0 + tx] : 0.f;
    }
    __syncthreads();
    #pragma unroll
    for (int i = 0; i < 32; i += 8) {
        int n = n0 + ty + i, k = k0 + tx;
        Bt[(size_t)n * Kpad + k] = f32_to_bf16(tile[tx][ty + i]);
    }
}

// ---------------- GEMM -> head-major C [10][MPAD][128] ----------------
// 128x128 tile, BK=32, double-buffered 32KB LDS (5 blocks/CU), XCD-bijective swizzle.
// LDS tile rows are 64B; 16B chunk phys = log ^ ((row>>1)&3) -> 2-way max bank conflict.
// AHM: A is head-major [10][MPAD][128] (layer 2); else row-major [MPAD][Kpad].

template <bool AHM>
__global__ __launch_bounds__(256) void k_gemm(const u16* __restrict__ A,
                                              const u16* __restrict__ Bt,
                                              u16* __restrict__ Chm,
                                              const int Kpad, const int kTiles) {
    __shared__ __attribute__((aligned(16))) u16 S[16384];  // A0,B0 @0/8192; A1,B1 @16384+
    const int bid = blockIdx.x;
    const int xcd = bid & 7, idx = bid >> 3;
    const int q = NWG >> 3, r = NWG & 7;
    const int L = (xcd < r) ? (xcd * (q + 1) + idx)
                            : (r * (q + 1) + (xcd - r) * q + idx);
    const size_t m0 = (size_t)(L / NT) * 128, n0 = (size_t)(L % NT) * 128;

    const int t = threadIdx.x;
    const int lane = t & 63;
    const int wave = t >> 6;
    const int wr = wave >> 1, wc = wave & 1;

    f32x4 acc[4][4] = {};

    // staging geometry: thread t, sub i in {0,1}: row = i*64 + (t>>2); phys chunk = t&3
    const int srow = t >> 2;
    const int klocal = (((t & 3) ^ ((t >> 3) & 3)) << 3);   // logical k elem within BK
    const u16* aRow = AHM ? (A + (m0 + srow) * 128 + klocal)
                          : (A + (m0 + srow) * (size_t)Kpad + klocal);
    const u16* bRow = Bt + (n0 + srow) * (size_t)Kpad + klocal;

#define STAGE(kt_, buf_) do {                                                    \
        char* db = (char*)S + (buf_) * 16384 + wave * 1024;                      \
        const u16* aP;                                                           \
        if (AHM) aP = aRow + (size_t)((kt_) >> 2) * (MPAD << 7) + ((kt_) & 3) * 32; \
        else     aP = aRow + (size_t)(kt_) * 32;                                 \
        const u16* bP = bRow + (size_t)(kt_) * 32;                               \
        const size_t aStep = AHM ? (size_t)64 * 128 : (size_t)64 * Kpad;         \
        gload16(aP,                 (u16*)(db));                                 \
        gload16(aP + aStep,         (u16*)(db + 4096));                          \
        gload16(bP,                 (u16*)(db + 8192));                          \
        gload16(bP + 64 * (size_t)Kpad, (u16*)(db + 12288));                     \
    } while (0)

    STAGE(0, 0);

    const int rl = lane & 15;
    const int pa = ((lane >> 4) ^ ((rl >> 1) & 3)) << 4;    // phys chunk byte offset
    const int aBase = (wr * 64 + rl) * 64 + pa;
    const int bBase = 8192 + (wc * 64 + rl) * 64 + pa;
    const char* Sb = (const char*)S;

    for (int kt = 0; kt < kTiles; ++kt) {
        asm volatile("s_waitcnt vmcnt(0)" ::: "memory");
        __builtin_amdgcn_s_barrier();
        if (kt + 1 < kTiles) STAGE(kt + 1, (kt + 1) & 1);
        const int bufo = (kt & 1) * 16384;
        bf16x8 af[4], bfr[4];
        #pragma unroll
        for (int mf = 0; mf < 4; ++mf)
            af[mf] = *(const bf16x8*)(Sb + bufo + aBase + mf * 1024);
        #pragma unroll
        for (int nf = 0; nf < 4; ++nf)
            bfr[nf] = *(const bf16x8*)(Sb + bufo + bBase + nf * 1024);
        #pragma unroll
        for (int mf = 0; mf < 4; ++mf)
            #pragma unroll
            for (int nf = 0; nf < 4; ++nf)
                acc[mf][nf] = __builtin_amdgcn_mfma_f32_16x16x32_bf16(
                    af[mf], bfr[nf], acc[mf][nf], 0, 0, 0);
    }
#undef STAGE

    // epilogue: head-major C write; this block's N-tile IS head n0>>7
    u16* Cb = Chm + (size_t)(n0 >> 7) * (MPAD << 7);
    #pragma unroll
    for (int mf = 0; mf < 4; ++mf)
        #pragma unroll
        for (int i = 0; i < 4; ++i) {
            size_t row = m0 + wr * 64 + mf * 16 + (lane >> 4) * 4 + i;
            u16* crow = Cb + row * 128 + wc * 64 + (lane & 15);
            #pragma unroll
            for (int nf = 0; nf < 4; ++nf)
                crow[nf * 16] = f32_to_bf16(acc[mf][nf][i]);
        }
}

// ---------------- attention coefficients: a_src/a_dst [10000][10] ----------------
__global__ __launch_bounds__(256) void k_attn(const u16* __restrict__ Hhm,
                                              const float* __restrict__ att_s,
                                              const float* __restrict__ att_d,
                                              float* __restrict__ a_src,
                                              float* __restrict__ a_dst) {
    const int lane = threadIdx.x & 63;
    const int n = blockIdx.x * 4 + (threadIdx.x >> 6);
    if (n >= NN) return;
    const unsigned* Hd = (const unsigned*)Hhm;
    #pragma unroll
    for (int h = 0; h < HEADS; ++h) {
        unsigned pv = Hd[((size_t)h * MPAD + n) * 64 + lane];
        float v0 = bf16lo(pv), v1 = bf16hi(pv);
        int c = h * 128 + lane * 2;
        float s = v0 * att_s[c] + v1 * att_s[c + 1];
        float d = v0 * att_d[c] + v1 * att_d[c + 1];
        #pragma unroll
        for (int o = 32; o; o >>= 1) { s += __shfl_xor(s, o); d += __shfl_xor(d, o); }
        if (lane == 0) { a_src[n * HEADS + h] = s; a_dst[n * HEADS + h] = d; }
    }
}

// ---------------- CSR build ----------------
__global__ void k_count(const int* __restrict__ ei, int* __restrict__ deg) {
    int e = blockIdx.x * blockDim.x + threadIdx.x;
    if (e >= ET) return;
    int d = (e < EE) ? ei[EE + e] : (e - EE);
    atomicAdd(&deg[d], 1);
}

__global__ __launch_bounds__(256) void k_scan(const int* __restrict__ deg,
                                              int* __restrict__ off,
                                              int* __restrict__ cursor) {
    __shared__ int wt[4];
    const int t = threadIdx.x, lane = t & 63, w = t >> 6;
    const int lo = t * 40;
    const int hi = (lo + 40 < NN) ? lo + 40 : NN;
    int s = 0;
    for (int i = lo; i < hi; ++i) s += deg[i];
    int x = s;
    #pragma unroll
    for (int o = 1; o < 64; o <<= 1) { int y = __shfl_up(x, o); if (lane >= o) x += y; }
    if (lane == 63) wt[w] = x;
    __syncthreads();
    int wp = 0;
    for (int k = 0; k < w; ++k) wp += wt[k];
    int run = wp + x - s;
    for (int i = lo; i < hi; ++i) { off[i] = run; cursor[i] = run; run += deg[i]; }
    if (t == 255) off[NN] = wp + x;
}

__global__ void k_scatter(const int* __restrict__ ei, int* __restrict__ cursor,
                          int* __restrict__ csr_src) {
    int e = blockIdx.x * blockDim.x + threadIdx.x;
    if (e >= ET) return;
    int s = (e < EE) ? ei[e] : (e - EE);
    int d = (e < EE) ? ei[EE + e] : (e - EE);
    int pos = atomicAdd(&cursor[d], 1);
    csr_src[pos] = s;
}

// ---------------- head-split aggregate, XCD-pinned ----------------
// grid = 8 * AGG_SLOTS; xcd = bid&7 owns head xcd (all nodes) + 1/8 of heads 8,9.
// Per-XCD L2 working set ~2.6-3 MB -> gathers are L2 hits.
// LAYER 1: A2hm[h][n][128] = bf16(relu(num/den + b1_h))
// LAYER 2: atomicAdd(out[n][c], 0.1*num/den)  (out pre-zeroed; k_final adds bias+relu)
template <int LAYER>
__global__ __launch_bounds__(256) void k_agg(const u16* __restrict__ Hhm,
                                             const float* __restrict__ a_src,
                                             const float* __restrict__ a_dst,
                                             const int* __restrict__ off,
                                             const int* __restrict__ csr,
                                             const float* __restrict__ bias,
                                             void* __restrict__ outp) {
    const int bid = blockIdx.x;
    const int xcd = bid & 7, slot = bid >> 3;
    const int wv = threadIdx.x >> 6, lane = threadIdx.x & 63;
    int h, n;
    if (slot < 2500) { h = xcd; n = slot * 4 + wv; }
    else {
        int s2 = slot - 2500;
        if (s2 < 313) { h = 8; n = xcd * 1250 + s2 * 4 + wv; }
        else          { h = 9; n = xcd * 1250 + (s2 - 313) * 4 + wv; }
        if (n >= (xcd + 1) * 1250) return;
    }
    if (n >= NN) return;

    const int beg = off[n], end = off[n + 1];
    const float ad = a_dst[n * HEADS + h];
    const unsigned* Hd = (const unsigned*)Hhm + (size_t)h * MPAD * 64;  // dword view
    const float* as = a_src;

    float acc0 = 0.f, acc1 = 0.f, den = 0.f;
    int i = beg;
    for (; i + 1 < end; i += 2) {
        int s0 = csr[i], s1 = csr[i + 1];
        float e0 = as[s0 * HEADS + h] + ad; e0 = (e0 >= 0.f) ? e0 : 0.2f * e0;
        float e1 = as[s1 * HEADS + h] + ad; e1 = (e1 >= 0.f) ? e1 : 0.2f * e1;
        unsigned p0 = Hd[s0 * 64 + lane];
        unsigned p1 = Hd[s1 * 64 + lane];
        float w0 = __expf(e0), w1 = __expf(e1);
        den += w0 + w1;
        acc0 = fmaf(bf16lo(p0), w0, acc0);
        acc1 = fmaf(bf16hi(p0), w0, acc1);
        acc0 = fmaf(bf16lo(p1), w1, acc0);
        acc1 = fmaf(bf16hi(p1), w1, acc1);
    }
    if (i < end) {
        int s0 = csr[i];
        float e0 = as[s0 * HEADS + h] + ad; e0 = (e0 >= 0.f) ? e0 : 0.2f * e0;
        float w0 = __expf(e0);
        unsigned p0 = Hd[s0 * 64 + lane];
        den += w0;
        acc0 = fmaf(bf16lo(p0), w0, acc0);
        acc1 = fmaf(bf16hi(p0), w0, acc1);
    }
    const float si = 1.f / (den + 1e-16f);

    if (LAYER == 1) {
        const int c = h * 128 + lane * 2;
        float v0 = fmaxf(fmaf(acc0, si, bias[c]), 0.f);
        float v1 = fmaxf(fmaf(acc1, si, bias[c + 1]), 0.f);
        ((unsigned*)outp)[((size_t)h * MPAD + n) * 64 + lane] =
            (unsigned)f32_to_bf16(v0) | ((unsigned)f32_to_bf16(v1) << 16);
    } else {
        float* orow = (float*)outp + (size_t)n * 128 + lane * 2;
        atomicAdd(orow,     acc0 * si * 0.1f);
        atomicAdd(orow + 1, acc1 * si * 0.1f);
    }
}

// zero pad rows NN..MPAD-1 of head-major A2 (10 slices)
__global__ __launch_bounds__(256) void k_zpad(unsigned* __restrict__ A2) {
    int idx = blockIdx.x * 256 + threadIdx.x;       // 10*112*64 = 71680 dwords
    if (idx >= 10 * 112 * 64) return;
    int h = idx / 7168, r = idx - h * 7168;
    int row = NN + (r >> 6), dw = r & 63;
    A2[((size_t)h * MPAD + row) * 64 + dw] = 0u;
}

// final: out = relu(out + b2)
__global__ __launch_bounds__(256) void k_final(float* __restrict__ out,
                                               const float* __restrict__ b2) {
    int i4 = blockIdx.x * 256 + threadIdx.x;        // 320000 f32x4
    if (i4 >= NN * 32) return;
    f32x4 v = *((f32x4*)out + i4);
    int c = (i4 & 31) * 4;
    #pragma unroll
    for (int j = 0; j < 4; ++j) v[j] = fmaxf(v[j] + b2[c + j], 0.f);
    *((f32x4*)out + i4) = v;
}

// ---------------- host ----------------
extern "C" void kernel_launch(void* const* d_in, const int* in_sizes, int n_in,
                              void* d_out, int out_size, void* d_ws, size_t ws_size,
                              hipStream_t stream) {
    const float* x   = (const float*)d_in[0];
    const int*   ei  = (const int*)  d_in[1];
    const float* W1  = (const float*)d_in[2];
    const float* as1 = (const float*)d_in[3];
    const float* ad1 = (const float*)d_in[4];
    const float* b1  = (const float*)d_in[5];
    const float* W2  = (const float*)d_in[6];
    const float* as2 = (const float*)d_in[7];
    const float* ad2 = (const float*)d_in[8];
    const float* b2  = (const float*)d_in[9];

    char* ws = (char*)d_ws;
    const size_t A1_OFF  = 0;                       // A1 [MPAD][2048] bf16 (41.4 MB)
    const size_t A2_OFF  = 0;                       // A2hm [10][MPAD][128] bf16 (25.9 MB)
    const size_t B2T_OFF = (size_t)MPAD * NH * 2;   // B2t [1280][1280] bf16 (3.3 MB)
    const size_t H_OFF   = (size_t)MPAD * K1PAD * 2;        // Hhm [10][MPAD][128]
    const size_t B1T_OFF = H_OFF + (size_t)MPAD * NH * 2;   // B1t [1280][2048]
    size_t o = B1T_OFF + (size_t)NH * K1PAD * 2;
    const size_t AS1_OFF = o; o += 400128;
    const size_t AD1_OFF = o; o += 400128;
    const size_t AS2_OFF = o; o += 400128;
    const size_t AD2_OFF = o; o += 400128;
    const size_t DEG_OFF = o; o += 40064;
    const size_t OFF_OFF = o; o += 40064;
    const size_t CUR_OFF = o; o += 40064;
    const size_t CSR_OFF = o; o += 680064;
    if (ws_size < o) return;

    u16*   A1   = (u16*)(ws + A1_OFF);
    u16*   A2   = (u16*)(ws + A2_OFF);
    u16*   B2t  = (u16*)(ws + B2T_OFF);
    u16*   H    = (u16*)(ws + H_OFF);
    u16*   B1t  = (u16*)(ws + B1T_OFF);
    float* aS1  = (float*)(ws + AS1_OFF);
    float* aD1  = (float*)(ws + AD1_OFF);
    float* aS2  = (float*)(ws + AS2_OFF);
    float* aD2  = (float*)(ws + AD2_OFF);
    int*   deg  = (int*)(ws + DEG_OFF);
    int*   offp = (int*)(ws + OFF_OFF);
    int*   cur  = (int*)(ws + CUR_OFF);
    int*   csr  = (int*)(ws + CSR_OFF);

    // CSR build
    hipMemsetAsync(deg, 0, NN * sizeof(int), stream);
    k_count<<<(ET + 255) / 256, 256, 0, stream>>>(ei, deg);
    k_scan<<<1, 256, 0, stream>>>(deg, offp, cur);
    k_scatter<<<(ET + 255) / 256, 256, 0, stream>>>(ei, cur, csr);

    // layer 1
    k_conv_x<<<2048, 256, 0, stream>>>(x, (uint2*)A1);
    k_convT<<<dim3(K1PAD / 32, NH / 32), dim3(32, 8), 0, stream>>>(W1, B1t, FIN, NH, K1PAD);
    k_gemm<false><<<NWG, 256, 0, stream>>>(A1, B1t, H, K1PAD, K1PAD / 32);
    k_attn<<<2500, 256, 0, stream>>>(H, as1, ad1, aS1, aD1);
    k_agg<1><<<8 * AGG_SLOTS, 256, 0, stream>>>(H, aS1, aD1, offp, csr, b1, A2);
    k_zpad<<<280, 256, 0, stream>>>((unsigned*)A2);

    // layer 2
    k_convT<<<dim3(NH / 32, NH / 32), dim3(32, 8), 0, stream>>>(W2, B2t, NH, NH, NH);
    k_gemm<true><<<NWG, 256, 0, stream>>>(A2, B2t, H, NH, NH / 32);
    k_attn<<<2500, 256, 0, stream>>>(H, as2, ad2, aS2, aD2);
    hipMemsetAsync(d_out, 0, (size_t)NN * 128 * sizeof(float), stream);
    k_agg<2><<<8 * AGG_SLOTS, 256, 0, stream>>>(H, aS2, aD2, offp, csr, b2, d_out);
    k_final<<<(NN * 32 + 255) / 256, 256, 0, stream>>>((float*)d_out, b2);
}

// Round 5
// 404.087 us; speedup vs baseline: 1.1292x; 1.1292x over previous
//
#include <hip/hip_runtime.h>

typedef unsigned short u16;
typedef __attribute__((ext_vector_type(8))) short bf16x8;
typedef __attribute__((ext_vector_type(4))) float f32x4;
typedef __attribute__((ext_vector_type(4))) unsigned u32x4;

#define NN    10000
#define EE    160000
#define ET    170000      // EE + NN self loops
#define FIN   2000
#define MPAD  10112       // 79*128
#define K1PAD 2048
#define NH    1280        // heads*channels
#define HEADS 10
#define NT    10          // N tiles (1280/128) == heads
#define NWG   790         // 79*10 gemm workgroups
#define AGG_BLOCKS 25000  // 8 XCD * 3125 slots * 4 waves = 100000 (n,h) units

__device__ __forceinline__ u16 f32_to_bf16(float f) {
    unsigned u = __float_as_uint(f);
    unsigned r = (u + 0x7fffu + ((u >> 16) & 1u)) >> 16;
    return (u16)r;
}
__device__ __forceinline__ float bf16lo(unsigned pv) { return __uint_as_float(pv << 16); }
__device__ __forceinline__ float bf16hi(unsigned pv) { return __uint_as_float(pv & 0xffff0000u); }

__device__ __forceinline__ void gload16(const u16* g, u16* l) {
    __builtin_amdgcn_global_load_lds(
        (const __attribute__((address_space(1))) void*)g,
        (__attribute__((address_space(3))) void*)l, 16, 0, 0);
}

// ---------------- conversion kernels ----------------

__global__ __launch_bounds__(256) void k_conv_x(const float* __restrict__ x,
                                                uint2* __restrict__ A1) {
    const int total = MPAD * (K1PAD / 4);
    for (int idx = blockIdx.x * 256 + threadIdx.x; idx < total; idx += gridDim.x * 256) {
        int r = idx >> 9;
        int c = (idx & 511) << 2;
        float4 v = make_float4(0.f, 0.f, 0.f, 0.f);
        if (r < NN && c < FIN) v = *(const float4*)(x + (size_t)r * FIN + c);
        uint2 p;
        p.x = (unsigned)f32_to_bf16(v.x) | ((unsigned)f32_to_bf16(v.y) << 16);
        p.y = (unsigned)f32_to_bf16(v.z) | ((unsigned)f32_to_bf16(v.w) << 16);
        A1[idx] = p;
    }
}

__global__ __launch_bounds__(256) void k_convT(const float* __restrict__ W,
                                               u16* __restrict__ Bt,
                                               int K, int Nn, int Kpad) {
    __shared__ float tile[32][33];
    int k0 = blockIdx.x * 32, n0 = blockIdx.y * 32;
    int tx = threadIdx.x, ty = threadIdx.y;   // (32,8)
    #pragma unroll
    for (int i = 0; i < 32; i += 8) {
        int k = k0 + ty + i;
        tile[ty + i][tx] = (k < K) ? W[(size_t)k * Nn + n0 + tx] : 0.f;
    }
    __syncthreads();
    #pragma unroll
    for (int i = 0; i < 32; i += 8) {
        int n = n0 + ty + i, k = k0 + tx;
        Bt[(size_t)n * Kpad + k] = f32_to_bf16(tile[tx][ty + i]);
    }
}

// ---------------- GEMM -> head-major C [10][MPAD][128] ----------------
// 128x128 tile, BK=32, double-buffered 32KB LDS (5 blocks/CU), XCD-bijective swizzle.

template <bool AHM>
__global__ __launch_bounds__(256) void k_gemm(const u16* __restrict__ A,
                                              const u16* __restrict__ Bt,
                                              u16* __restrict__ Chm,
                                              const int Kpad, const int kTiles) {
    __shared__ __attribute__((aligned(16))) u16 S[16384];
    const int bid = blockIdx.x;
    const int xcd = bid & 7, idx = bid >> 3;
    const int q = NWG >> 3, r = NWG & 7;
    const int L = (xcd < r) ? (xcd * (q + 1) + idx)
                            : (r * (q + 1) + (xcd - r) * q + idx);
    const size_t m0 = (size_t)(L / NT) * 128, n0 = (size_t)(L % NT) * 128;

    const int t = threadIdx.x;
    const int lane = t & 63;
    const int wave = t >> 6;
    const int wr = wave >> 1, wc = wave & 1;

    f32x4 acc[4][4] = {};

    const int srow = t >> 2;
    const int klocal = (((t & 3) ^ ((t >> 3) & 3)) << 3);
    const u16* aRow = AHM ? (A + (m0 + srow) * 128 + klocal)
                          : (A + (m0 + srow) * (size_t)Kpad + klocal);
    const u16* bRow = Bt + (n0 + srow) * (size_t)Kpad + klocal;

#define STAGE(kt_, buf_) do {                                                    \
        char* db = (char*)S + (buf_) * 16384 + wave * 1024;                      \
        const u16* aP;                                                           \
        if (AHM) aP = aRow + (size_t)((kt_) >> 2) * (MPAD << 7) + ((kt_) & 3) * 32; \
        else     aP = aRow + (size_t)(kt_) * 32;                                 \
        const u16* bP = bRow + (size_t)(kt_) * 32;                               \
        const size_t aStep = AHM ? (size_t)64 * 128 : (size_t)64 * Kpad;         \
        gload16(aP,                 (u16*)(db));                                 \
        gload16(aP + aStep,         (u16*)(db + 4096));                          \
        gload16(bP,                 (u16*)(db + 8192));                          \
        gload16(bP + 64 * (size_t)Kpad, (u16*)(db + 12288));                     \
    } while (0)

    STAGE(0, 0);

    const int rl = lane & 15;
    const int pa = ((lane >> 4) ^ ((rl >> 1) & 3)) << 4;
    const int aBase = (wr * 64 + rl) * 64 + pa;
    const int bBase = 8192 + (wc * 64 + rl) * 64 + pa;
    const char* Sb = (const char*)S;

    for (int kt = 0; kt < kTiles; ++kt) {
        asm volatile("s_waitcnt vmcnt(0)" ::: "memory");
        __builtin_amdgcn_s_barrier();
        if (kt + 1 < kTiles) STAGE(kt + 1, (kt + 1) & 1);
        const int bufo = (kt & 1) * 16384;
        bf16x8 af[4], bfr[4];
        #pragma unroll
        for (int mf = 0; mf < 4; ++mf)
            af[mf] = *(const bf16x8*)(Sb + bufo + aBase + mf * 1024);
        #pragma unroll
        for (int nf = 0; nf < 4; ++nf)
            bfr[nf] = *(const bf16x8*)(Sb + bufo + bBase + nf * 1024);
        #pragma unroll
        for (int mf = 0; mf < 4; ++mf)
            #pragma unroll
            for (int nf = 0; nf < 4; ++nf)
                acc[mf][nf] = __builtin_amdgcn_mfma_f32_16x16x32_bf16(
                    af[mf], bfr[nf], acc[mf][nf], 0, 0, 0);
    }
#undef STAGE

    u16* Cb = Chm + (size_t)(n0 >> 7) * (MPAD << 7);
    #pragma unroll
    for (int mf = 0; mf < 4; ++mf)
        #pragma unroll
        for (int i = 0; i < 4; ++i) {
            size_t row = m0 + wr * 64 + mf * 16 + (lane >> 4) * 4 + i;
            u16* crow = Cb + row * 128 + wc * 64 + (lane & 15);
            #pragma unroll
            for (int nf = 0; nf < 4; ++nf)
                crow[nf * 16] = f32_to_bf16(acc[mf][nf][i]);
        }
}

// ---------------- attention coefficients: a_src/a_dst [10000][10] ----------------
__global__ __launch_bounds__(256) void k_attn(const u16* __restrict__ Hhm,
                                              const float* __restrict__ att_s,
                                              const float* __restrict__ att_d,
                                              float* __restrict__ a_src,
                                              float* __restrict__ a_dst) {
    const int lane = threadIdx.x & 63;
    const int n = blockIdx.x * 4 + (threadIdx.x >> 6);
    if (n >= NN) return;
    const unsigned* Hd = (const unsigned*)Hhm;
    #pragma unroll
    for (int h = 0; h < HEADS; ++h) {
        unsigned pv = Hd[((size_t)h * MPAD + n) * 64 + lane];
        float v0 = bf16lo(pv), v1 = bf16hi(pv);
        int c = h * 128 + lane * 2;
        float s = v0 * att_s[c] + v1 * att_s[c + 1];
        float d = v0 * att_d[c] + v1 * att_d[c + 1];
        #pragma unroll
        for (int o = 32; o; o >>= 1) { s += __shfl_xor(s, o); d += __shfl_xor(d, o); }
        if (lane == 0) { a_src[n * HEADS + h] = s; a_dst[n * HEADS + h] = d; }
    }
}

// ---------------- CSR build ----------------
__global__ void k_count(const int* __restrict__ ei, int* __restrict__ deg) {
    int e = blockIdx.x * blockDim.x + threadIdx.x;
    if (e >= ET) return;
    int d = (e < EE) ? ei[EE + e] : (e - EE);
    atomicAdd(&deg[d], 1);
}

__global__ __launch_bounds__(256) void k_scan(const int* __restrict__ deg,
                                              int* __restrict__ off,
                                              int* __restrict__ cursor) {
    __shared__ int wt[4];
    const int t = threadIdx.x, lane = t & 63, w = t >> 6;
    const int lo = t * 40;
    const int hi = (lo + 40 < NN) ? lo + 40 : NN;
    int s = 0;
    for (int i = lo; i < hi; ++i) s += deg[i];
    int x = s;
    #pragma unroll
    for (int o = 1; o < 64; o <<= 1) { int y = __shfl_up(x, o); if (lane >= o) x += y; }
    if (lane == 63) wt[w] = x;
    __syncthreads();
    int wp = 0;
    for (int k = 0; k < w; ++k) wp += wt[k];
    int run = wp + x - s;
    for (int i = lo; i < hi; ++i) { off[i] = run; cursor[i] = run; run += deg[i]; }
    if (t == 255) off[NN] = wp + x;
}

__global__ void k_scatter(const int* __restrict__ ei, int* __restrict__ cursor,
                          int* __restrict__ csr_src) {
    int e = blockIdx.x * blockDim.x + threadIdx.x;
    if (e >= ET) return;
    int s = (e < EE) ? ei[e] : (e - EE);
    int d = (e < EE) ? ei[EE + e] : (e - EE);
    int pos = atomicAdd(&cursor[d], 1);
    csr_src[pos] = s;
}

// ---------------- head-split aggregate: XCD-pinned, 4 edges/wave-iter ----------------
// One wave per (node, head). Lane = (edge-group g=lane>>4, chan-slice l=lane&15).
// Per iteration: 4 edges; each lane: one u32x4 H gather (1024B/wave-inst), one
// broadcast a_src load, one exp per 4 edges. shfl_xor(16,32) folds edge-groups.
// XCD x owns head x (all nodes) + 1/8 node-slice of heads 8,9 -> ~3MB L2 set.
template <int LAYER>
__global__ __launch_bounds__(256) void k_agg(const u16* __restrict__ Hhm,
                                             const float* __restrict__ a_src,
                                             const float* __restrict__ a_dst,
                                             const int* __restrict__ off,
                                             const int* __restrict__ csr,
                                             const float* __restrict__ bias,
                                             void* __restrict__ outp) {
    const int bid = blockIdx.x;
    const int xcd = bid & 7, slot = bid >> 3;
    const int wv = threadIdx.x >> 6, lane = threadIdx.x & 63;
    const int unit = slot * 4 + wv;            // [0, 12500)
    int h, n;
    if (unit < 10000) { h = xcd; n = unit; }
    else {
        int u2 = unit - 10000;                 // [0, 2500)
        h = 8 + (u2 >= 1250);
        n = xcd * 1250 + (u2 >= 1250 ? u2 - 1250 : u2);
    }
    const int beg = off[n], end = off[n + 1];
    const int g = lane >> 4, l = lane & 15;
    const float ad = a_dst[n * HEADS + h];
    const u16* Hh = Hhm + (size_t)h * (MPAD * 128);

    float acc[8] = {};
    float den = 0.f;
    for (int i = beg + g; i < end; i += 4) {
        const int s = csr[i];
        float e = a_src[s * HEADS + h] + ad; e = (e >= 0.f) ? e : 0.2f * e;
        const float w = __expf(e);
        den += w;
        const u32x4 v = *(const u32x4*)(Hh + (size_t)s * 128 + l * 8);
        #pragma unroll
        for (int j = 0; j < 4; ++j) {
            acc[2 * j]     = fmaf(bf16lo(v[j]), w, acc[2 * j]);
            acc[2 * j + 1] = fmaf(bf16hi(v[j]), w, acc[2 * j + 1]);
        }
    }
    #pragma unroll
    for (int j = 0; j < 8; ++j) {
        acc[j] += __shfl_xor(acc[j], 16);
        acc[j] += __shfl_xor(acc[j], 32);
    }
    den += __shfl_xor(den, 16);
    den += __shfl_xor(den, 32);
    const float si = 1.f / (den + 1e-16f);

    if (LAYER == 1) {
        // dword d = l*4+g covers channels l*8+2g, l*8+2g+1; all 64 lanes store 256B
        const int c = h * 128 + l * 8 + 2 * g;
        float v0 = fmaxf(fmaf(acc[2 * g],     si, bias[c]),     0.f);
        float v1 = fmaxf(fmaf(acc[2 * g + 1], si, bias[c + 1]), 0.f);
        ((unsigned*)outp)[(size_t)h * (MPAD * 64) + (size_t)n * 64 + l * 4 + g] =
            (unsigned)f32_to_bf16(v0) | ((unsigned)f32_to_bf16(v1) << 16);
    } else {
        // each group atomics 2 of its slice's 8 channels -> 2 all-lane atomic insts
        float* orow = (float*)outp + (size_t)n * 128 + l * 8 + g * 2;
        atomicAdd(orow,     acc[2 * g]     * si * 0.1f);
        atomicAdd(orow + 1, acc[2 * g + 1] * si * 0.1f);
    }
}

// zero pad rows NN..MPAD-1 of head-major A2 (10 slices)
__global__ __launch_bounds__(256) void k_zpad(unsigned* __restrict__ A2) {
    int idx = blockIdx.x * 256 + threadIdx.x;       // 10*112*64 = 71680 dwords
    if (idx >= 10 * 112 * 64) return;
    int h = idx / 7168, r = idx - h * 7168;
    int row = NN + (r >> 6), dw = r & 63;
    A2[((size_t)h * MPAD + row) * 64 + dw] = 0u;
}

// final: out = relu(out + b2)
__global__ __launch_bounds__(256) void k_final(float* __restrict__ out,
                                               const float* __restrict__ b2) {
    int i4 = blockIdx.x * 256 + threadIdx.x;        // 320000 f32x4
    if (i4 >= NN * 32) return;
    f32x4 v = *((f32x4*)out + i4);
    int c = (i4 & 31) * 4;
    #pragma unroll
    for (int j = 0; j < 4; ++j) v[j] = fmaxf(v[j] + b2[c + j], 0.f);
    *((f32x4*)out + i4) = v;
}

// ---------------- host ----------------
extern "C" void kernel_launch(void* const* d_in, const int* in_sizes, int n_in,
                              void* d_out, int out_size, void* d_ws, size_t ws_size,
                              hipStream_t stream) {
    const float* x   = (const float*)d_in[0];
    const int*   ei  = (const int*)  d_in[1];
    const float* W1  = (const float*)d_in[2];
    const float* as1 = (const float*)d_in[3];
    const float* ad1 = (const float*)d_in[4];
    const float* b1  = (const float*)d_in[5];
    const float* W2  = (const float*)d_in[6];
    const float* as2 = (const float*)d_in[7];
    const float* ad2 = (const float*)d_in[8];
    const float* b2  = (const float*)d_in[9];

    char* ws = (char*)d_ws;
    const size_t A1_OFF  = 0;                       // A1 [MPAD][2048] bf16
    const size_t A2_OFF  = 0;                       // A2hm [10][MPAD][128] bf16
    const size_t B2T_OFF = (size_t)MPAD * NH * 2;   // B2t [1280][1280] bf16
    const size_t H_OFF   = (size_t)MPAD * K1PAD * 2;        // Hhm [10][MPAD][128]
    const size_t B1T_OFF = H_OFF + (size_t)MPAD * NH * 2;   // B1t [1280][2048]
    size_t o = B1T_OFF + (size_t)NH * K1PAD * 2;
    const size_t AS1_OFF = o; o += 400128;
    const size_t AD1_OFF = o; o += 400128;
    const size_t AS2_OFF = o; o += 400128;
    const size_t AD2_OFF = o; o += 400128;
    const size_t DEG_OFF = o; o += 40064;
    const size_t OFF_OFF = o; o += 40064;
    const size_t CUR_OFF = o; o += 40064;
    const size_t CSR_OFF = o; o += 680064;
    if (ws_size < o) return;

    u16*   A1   = (u16*)(ws + A1_OFF);
    u16*   A2   = (u16*)(ws + A2_OFF);
    u16*   B2t  = (u16*)(ws + B2T_OFF);
    u16*   H    = (u16*)(ws + H_OFF);
    u16*   B1t  = (u16*)(ws + B1T_OFF);
    float* aS1  = (float*)(ws + AS1_OFF);
    float* aD1  = (float*)(ws + AD1_OFF);
    float* aS2  = (float*)(ws + AS2_OFF);
    float* aD2  = (float*)(ws + AD2_OFF);
    int*   deg  = (int*)(ws + DEG_OFF);
    int*   offp = (int*)(ws + OFF_OFF);
    int*   cur  = (int*)(ws + CUR_OFF);
    int*   csr  = (int*)(ws + CSR_OFF);

    // CSR build
    hipMemsetAsync(deg, 0, NN * sizeof(int), stream);
    k_count<<<(ET + 255) / 256, 256, 0, stream>>>(ei, deg);
    k_scan<<<1, 256, 0, stream>>>(deg, offp, cur);
    k_scatter<<<(ET + 255) / 256, 256, 0, stream>>>(ei, cur, csr);

    // layer 1
    k_conv_x<<<2048, 256, 0, stream>>>(x, (uint2*)A1);
    k_convT<<<dim3(K1PAD / 32, NH / 32), dim3(32, 8), 0, stream>>>(W1, B1t, FIN, NH, K1PAD);
    k_gemm<false><<<NWG, 256, 0, stream>>>(A1, B1t, H, K1PAD, K1PAD / 32);
    k_attn<<<2500, 256, 0, stream>>>(H, as1, ad1, aS1, aD1);
    k_agg<1><<<AGG_BLOCKS, 256, 0, stream>>>(H, aS1, aD1, offp, csr, b1, A2);
    k_zpad<<<280, 256, 0, stream>>>((unsigned*)A2);

    // layer 2
    k_convT<<<dim3(NH / 32, NH / 32), dim3(32, 8), 0, stream>>>(W2, B2t, NH, NH, NH);
    k_gemm<true><<<NWG, 256, 0, stream>>>(A2, B2t, H, NH, NH / 32);
    k_attn<<<2500, 256, 0, stream>>>(H, as2, ad2, aS2, aD2);
    hipMemsetAsync(d_out, 0, (size_t)NN * 128 * sizeof(float), stream);
    k_agg<2><<<AGG_BLOCKS, 256, 0, stream>>>(H, aS2, aD2, offp, csr, b2, d_out);
    k_final<<<(NN * 32 + 255) / 256, 256, 0, stream>>>((float*)d_out, b2);
}

// Round 6
// 342.096 us; speedup vs baseline: 1.3338x; 1.1812x over previous
//
#include <hip/hip_runtime.h>

typedef unsigned short u16;
typedef __attribute__((ext_vector_type(8))) short bf16x8;
typedef __attribute__((ext_vector_type(4))) float f32x4;
typedef __attribute__((ext_vector_type(4))) unsigned u32x4;

#define NN    10000
#define EE    160000
#define ET    170000      // EE + NN self loops
#define FIN   2000
#define MPAD  10112       // 79*128
#define K1PAD 2048
#define NH    1280        // heads*channels
#define HEADS 10
#define NT    10          // N tiles (1280/128) == heads
#define NWG   790         // 79*10 gemm workgroups

__device__ __forceinline__ u16 f32_to_bf16(float f) {
    unsigned u = __float_as_uint(f);
    unsigned r = (u + 0x7fffu + ((u >> 16) & 1u)) >> 16;
    return (u16)r;
}
__device__ __forceinline__ float bf16lo(unsigned pv) { return __uint_as_float(pv << 16); }
__device__ __forceinline__ float bf16hi(unsigned pv) { return __uint_as_float(pv & 0xffff0000u); }

__device__ __forceinline__ void gload16(const u16* g, u16* l) {
    __builtin_amdgcn_global_load_lds(
        (const __attribute__((address_space(1))) void*)g,
        (__attribute__((address_space(3))) void*)l, 16, 0, 0);
}

// ---------------- conversion kernels ----------------

__global__ __launch_bounds__(256) void k_conv_x(const float* __restrict__ x,
                                                uint2* __restrict__ A1) {
    const int total = MPAD * (K1PAD / 4);
    for (int idx = blockIdx.x * 256 + threadIdx.x; idx < total; idx += gridDim.x * 256) {
        int r = idx >> 9;
        int c = (idx & 511) << 2;
        float4 v = make_float4(0.f, 0.f, 0.f, 0.f);
        if (r < NN && c < FIN) v = *(const float4*)(x + (size_t)r * FIN + c);
        uint2 p;
        p.x = (unsigned)f32_to_bf16(v.x) | ((unsigned)f32_to_bf16(v.y) << 16);
        p.y = (unsigned)f32_to_bf16(v.z) | ((unsigned)f32_to_bf16(v.w) << 16);
        A1[idx] = p;
    }
}

__global__ __launch_bounds__(256) void k_convT(const float* __restrict__ W,
                                               u16* __restrict__ Bt,
                                               int K, int Nn, int Kpad) {
    __shared__ float tile[32][33];
    int k0 = blockIdx.x * 32, n0 = blockIdx.y * 32;
    int tx = threadIdx.x, ty = threadIdx.y;   // (32,8)
    #pragma unroll
    for (int i = 0; i < 32; i += 8) {
        int k = k0 + ty + i;
        tile[ty + i][tx] = (k < K) ? W[(size_t)k * Nn + n0 + tx] : 0.f;
    }
    __syncthreads();
    #pragma unroll
    for (int i = 0; i < 32; i += 8) {
        int n = n0 + ty + i, k = k0 + tx;
        Bt[(size_t)n * Kpad + k] = f32_to_bf16(tile[tx][ty + i]);
    }
}

// ---------------- GEMM -> head-major C [10][MPAD][128] ----------------
// 128x128 tile, BK=32, double-buffered 32KB LDS, XCD-bijective swizzle.

template <bool AHM>
__global__ __launch_bounds__(256) void k_gemm(const u16* __restrict__ A,
                                              const u16* __restrict__ Bt,
                                              u16* __restrict__ Chm,
                                              const int Kpad, const int kTiles) {
    __shared__ __attribute__((aligned(16))) u16 S[16384];
    const int bid = blockIdx.x;
    const int xcd = bid & 7, idx = bid >> 3;
    const int q = NWG >> 3, r = NWG & 7;
    const int L = (xcd < r) ? (xcd * (q + 1) + idx)
                            : (r * (q + 1) + (xcd - r) * q + idx);
    const size_t m0 = (size_t)(L / NT) * 128, n0 = (size_t)(L % NT) * 128;

    const int t = threadIdx.x;
    const int lane = t & 63;
    const int wave = t >> 6;
    const int wr = wave >> 1, wc = wave & 1;

    f32x4 acc[4][4] = {};

    const int srow = t >> 2;
    const int klocal = (((t & 3) ^ ((t >> 3) & 3)) << 3);
    const u16* aRow = AHM ? (A + (m0 + srow) * 128 + klocal)
                          : (A + (m0 + srow) * (size_t)Kpad + klocal);
    const u16* bRow = Bt + (n0 + srow) * (size_t)Kpad + klocal;

#define STAGE(kt_, buf_) do {                                                    \
        char* db = (char*)S + (buf_) * 16384 + wave * 1024;                      \
        const u16* aP;                                                           \
        if (AHM) aP = aRow + (size_t)((kt_) >> 2) * (MPAD << 7) + ((kt_) & 3) * 32; \
        else     aP = aRow + (size_t)(kt_) * 32;                                 \
        const u16* bP = bRow + (size_t)(kt_) * 32;                               \
        const size_t aStep = AHM ? (size_t)64 * 128 : (size_t)64 * Kpad;         \
        gload16(aP,                 (u16*)(db));                                 \
        gload16(aP + aStep,         (u16*)(db + 4096));                          \
        gload16(bP,                 (u16*)(db + 8192));                          \
        gload16(bP + 64 * (size_t)Kpad, (u16*)(db + 12288));                     \
    } while (0)

    STAGE(0, 0);

    const int rl = lane & 15;
    const int pa = ((lane >> 4) ^ ((rl >> 1) & 3)) << 4;
    const int aBase = (wr * 64 + rl) * 64 + pa;
    const int bBase = 8192 + (wc * 64 + rl) * 64 + pa;
    const char* Sb = (const char*)S;

    for (int kt = 0; kt < kTiles; ++kt) {
        asm volatile("s_waitcnt vmcnt(0)" ::: "memory");
        __builtin_amdgcn_s_barrier();
        if (kt + 1 < kTiles) STAGE(kt + 1, (kt + 1) & 1);
        const int bufo = (kt & 1) * 16384;
        bf16x8 af[4], bfr[4];
        #pragma unroll
        for (int mf = 0; mf < 4; ++mf)
            af[mf] = *(const bf16x8*)(Sb + bufo + aBase + mf * 1024);
        #pragma unroll
        for (int nf = 0; nf < 4; ++nf)
            bfr[nf] = *(const bf16x8*)(Sb + bufo + bBase + nf * 1024);
        #pragma unroll
        for (int mf = 0; mf < 4; ++mf)
            #pragma unroll
            for (int nf = 0; nf < 4; ++nf)
                acc[mf][nf] = __builtin_amdgcn_mfma_f32_16x16x32_bf16(
                    af[mf], bfr[nf], acc[mf][nf], 0, 0, 0);
    }
#undef STAGE

    u16* Cb = Chm + (size_t)(n0 >> 7) * (MPAD << 7);
    #pragma unroll
    for (int mf = 0; mf < 4; ++mf)
        #pragma unroll
        for (int i = 0; i < 4; ++i) {
            size_t row = m0 + wr * 64 + mf * 16 + (lane >> 4) * 4 + i;
            u16* crow = Cb + row * 128 + wc * 64 + (lane & 15);
            #pragma unroll
            for (int nf = 0; nf < 4; ++nf)
                crow[nf * 16] = f32_to_bf16(acc[mf][nf][i]);
        }
}

// ---------------- attention coefficients: a_src/a_dst [10000][10] ----------------
__global__ __launch_bounds__(256) void k_attn(const u16* __restrict__ Hhm,
                                              const float* __restrict__ att_s,
                                              const float* __restrict__ att_d,
                                              float* __restrict__ a_src,
                                              float* __restrict__ a_dst) {
    const int lane = threadIdx.x & 63;
    const int n = blockIdx.x * 4 + (threadIdx.x >> 6);
    if (n >= NN) return;
    const unsigned* Hd = (const unsigned*)Hhm;
    #pragma unroll
    for (int h = 0; h < HEADS; ++h) {
        unsigned pv = Hd[((size_t)h * MPAD + n) * 64 + lane];
        float v0 = bf16lo(pv), v1 = bf16hi(pv);
        int c = h * 128 + lane * 2;
        float s = v0 * att_s[c] + v1 * att_s[c + 1];
        float d = v0 * att_d[c] + v1 * att_d[c + 1];
        #pragma unroll
        for (int o = 32; o; o >>= 1) { s += __shfl_xor(s, o); d += __shfl_xor(d, o); }
        if (lane == 0) { a_src[n * HEADS + h] = s; a_dst[n * HEADS + h] = d; }
    }
}

// ---------------- CSR build ----------------
__global__ void k_count(const int* __restrict__ ei, int* __restrict__ deg) {
    int e = blockIdx.x * blockDim.x + threadIdx.x;
    if (e >= ET) return;
    int d = (e < EE) ? ei[EE + e] : (e - EE);
    atomicAdd(&deg[d], 1);
}

__global__ __launch_bounds__(256) void k_scan(const int* __restrict__ deg,
                                              int* __restrict__ off,
                                              int* __restrict__ cursor) {
    __shared__ int wt[4];
    const int t = threadIdx.x, lane = t & 63, w = t >> 6;
    const int lo = t * 40;
    const int hi = (lo + 40 < NN) ? lo + 40 : NN;
    int s = 0;
    for (int i = lo; i < hi; ++i) s += deg[i];
    int x = s;
    #pragma unroll
    for (int o = 1; o < 64; o <<= 1) { int y = __shfl_up(x, o); if (lane >= o) x += y; }
    if (lane == 63) wt[w] = x;
    __syncthreads();
    int wp = 0;
    for (int k = 0; k < w; ++k) wp += wt[k];
    int run = wp + x - s;
    for (int i = lo; i < hi; ++i) { off[i] = run; cursor[i] = run; run += deg[i]; }
    if (t == 255) off[NN] = wp + x;
}

__global__ void k_scatter(const int* __restrict__ ei, int* __restrict__ cursor,
                          int* __restrict__ csr_src, int* __restrict__ csr_dst) {
    int e = blockIdx.x * blockDim.x + threadIdx.x;
    if (e >= ET) return;
    int s = (e < EE) ? ei[e] : (e - EE);
    int d = (e < EE) ? ei[EE + e] : (e - EE);
    int pos = atomicAdd(&cursor[d], 1);
    csr_src[pos] = s;
    csr_dst[pos] = d;
}

// ---------------- edge weights: wbuf[h][i] = exp(leaky(a_src[s][h]+a_dst[d][h])) ---
__global__ __launch_bounds__(256) void k_edgew(const float* __restrict__ a_src,
                                               const float* __restrict__ a_dst,
                                               const int* __restrict__ csr_s,
                                               const int* __restrict__ csr_d,
                                               float* __restrict__ wbuf) {
    int i = blockIdx.x * 256 + threadIdx.x;
    if (i >= ET) return;
    const int s = csr_s[i], d = csr_d[i];
    const float* ps = a_src + (size_t)s * HEADS;
    const float* pd = a_dst + (size_t)d * HEADS;
    #pragma unroll
    for (int h = 0; h < HEADS; ++h) {
        float e = ps[h] + pd[h];
        e = (e >= 0.f) ? e : 0.2f * e;
        wbuf[(size_t)h * ET + i] = __expf(e);
    }
}

// ---------------- head-split aggregate: wave = (head, 4 nodes) -------------------
// 16-lane group g owns node q*4+g: full 256B row slice per gather, den replicated
// within group (no cross-lane reduce). XCD x pinned to head x (+ slice of 8/9).
// LAYER 1: out = bf16(relu(num*si + b1))  -> A2hm[h][n][128]
// LAYER 2: out = bf16(num*si)             -> Z[h][n][128]  (k_final sums heads)
template <int LAYER>
__global__ __launch_bounds__(256) void k_agg(const u16* __restrict__ Hhm,
                                             const float* __restrict__ wbuf,
                                             const int* __restrict__ off,
                                             const int* __restrict__ csr,
                                             const float* __restrict__ bias,
                                             unsigned* __restrict__ outp) {
    const int bid = blockIdx.x;
    const int xcd = bid & 7, slot = bid >> 3;
    const int wv = threadIdx.x >> 6, lane = threadIdx.x & 63;
    const int u = slot * 4 + wv;               // [0, 3128)
    if (u >= 3125) return;
    int h, qd;
    if (u < 2500) { h = xcd; qd = u; }
    else {
        int qg = xcd * 625 + (u - 2500);       // [0, 5000)
        h = 8 + (qg >= 2500);
        qd = (qg >= 2500) ? qg - 2500 : qg;
    }
    const int g = lane >> 4, l = lane & 15;
    const int n = qd * 4 + g;
    const int beg = off[n], end = off[n + 1];
    const u16* Hh = Hhm + (size_t)h * (MPAD * 128);
    const float* wp = wbuf + (size_t)h * ET;

    float acc[8] = {};
    float den = 0.f;
    int i = beg;
    for (; i + 1 < end; i += 2) {
        const int s0 = csr[i], s1 = csr[i + 1];
        const float w0 = wp[i], w1 = wp[i + 1];
        const u32x4 v0 = *(const u32x4*)(Hh + (size_t)s0 * 128 + l * 8);
        const u32x4 v1 = *(const u32x4*)(Hh + (size_t)s1 * 128 + l * 8);
        den += w0 + w1;
        #pragma unroll
        for (int j = 0; j < 4; ++j) {
            acc[2 * j]     = fmaf(bf16lo(v0[j]), w0, acc[2 * j]);
            acc[2 * j + 1] = fmaf(bf16hi(v0[j]), w0, acc[2 * j + 1]);
            acc[2 * j]     = fmaf(bf16lo(v1[j]), w1, acc[2 * j]);
            acc[2 * j + 1] = fmaf(bf16hi(v1[j]), w1, acc[2 * j + 1]);
        }
    }
    if (i < end) {
        const int s0 = csr[i];
        const float w0 = wp[i];
        const u32x4 v0 = *(const u32x4*)(Hh + (size_t)s0 * 128 + l * 8);
        den += w0;
        #pragma unroll
        for (int j = 0; j < 4; ++j) {
            acc[2 * j]     = fmaf(bf16lo(v0[j]), w0, acc[2 * j]);
            acc[2 * j + 1] = fmaf(bf16hi(v0[j]), w0, acc[2 * j + 1]);
        }
    }
    const float si = 1.f / (den + 1e-16f);

    u32x4 pk;
    if (LAYER == 1) {
        const int c = h * 128 + l * 8;
        #pragma unroll
        for (int j = 0; j < 4; ++j) {
            float v0 = fmaxf(fmaf(acc[2 * j],     si, bias[c + 2 * j]),     0.f);
            float v1 = fmaxf(fmaf(acc[2 * j + 1], si, bias[c + 2 * j + 1]), 0.f);
            pk[j] = (unsigned)f32_to_bf16(v0) | ((unsigned)f32_to_bf16(v1) << 16);
        }
    } else {
        #pragma unroll
        for (int j = 0; j < 4; ++j) {
            pk[j] = (unsigned)f32_to_bf16(acc[2 * j] * si)
                  | ((unsigned)f32_to_bf16(acc[2 * j + 1] * si) << 16);
        }
    }
    *(u32x4*)(outp + (size_t)h * (MPAD * 64) + (size_t)n * 64 + l * 4) = pk;
}

// zero pad rows NN..MPAD-1 of head-major A2 (10 slices)
__global__ __launch_bounds__(256) void k_zpad(unsigned* __restrict__ A2) {
    int idx = blockIdx.x * 256 + threadIdx.x;       // 10*112*64 = 71680 dwords
    if (idx >= 10 * 112 * 64) return;
    int h = idx / 7168, r = idx - h * 7168;
    int row = NN + (r >> 6), dw = r & 63;
    A2[((size_t)h * MPAD + row) * 64 + dw] = 0u;
}

// final: out[n][c] = relu(0.1 * sum_h Z[h][n][c] + b2[c])
__global__ __launch_bounds__(256) void k_final(const unsigned* __restrict__ Z,
                                               const float* __restrict__ b2,
                                               float* __restrict__ out) {
    int t = blockIdx.x * 256 + threadIdx.x;         // NN*64 dword slots
    if (t >= NN * 64) return;
    int n = t >> 6, d = t & 63;
    float s0 = 0.f, s1 = 0.f;
    #pragma unroll
    for (int h = 0; h < HEADS; ++h) {
        unsigned pv = Z[(size_t)h * (MPAD * 64) + (size_t)n * 64 + d];
        s0 += bf16lo(pv);
        s1 += bf16hi(pv);
    }
    float2 z;
    z.x = fmaxf(fmaf(s0, 0.1f, b2[2 * d]),     0.f);
    z.y = fmaxf(fmaf(s1, 0.1f, b2[2 * d + 1]), 0.f);
    *(float2*)(out + (size_t)n * 128 + 2 * d) = z;
}

// ---------------- host ----------------
extern "C" void kernel_launch(void* const* d_in, const int* in_sizes, int n_in,
                              void* d_out, int out_size, void* d_ws, size_t ws_size,
                              hipStream_t stream) {
    const float* x   = (const float*)d_in[0];
    const int*   ei  = (const int*)  d_in[1];
    const float* W1  = (const float*)d_in[2];
    const float* as1 = (const float*)d_in[3];
    const float* ad1 = (const float*)d_in[4];
    const float* b1  = (const float*)d_in[5];
    const float* W2  = (const float*)d_in[6];
    const float* as2 = (const float*)d_in[7];
    const float* ad2 = (const float*)d_in[8];
    const float* b2  = (const float*)d_in[9];

    char* ws = (char*)d_ws;
    const size_t A1_OFF  = 0;                       // A1 [MPAD][2048] bf16 (41.4MB)
    const size_t A2_OFF  = 0;                       // A2hm / Z [10][MPAD][128] bf16
    const size_t B2T_OFF = (size_t)MPAD * NH * 2;   // 25,886,720 (+3.28MB)
    const size_t WB_OFF  = B2T_OFF + (size_t)NH * NH * 2;   // 29,163,520 (+6.8MB)
    const size_t H_OFF   = (size_t)MPAD * K1PAD * 2;        // 41,418,752
    const size_t B1T_OFF = H_OFF + (size_t)MPAD * NH * 2;   // 67,305,472
    size_t o = B1T_OFF + (size_t)NH * K1PAD * 2;
    const size_t AS_OFF  = o; o += 400128;
    const size_t AD_OFF  = o; o += 400128;
    const size_t DEG_OFF = o; o += 40064;
    const size_t OFF_OFF = o; o += 40064;
    const size_t CUR_OFF = o; o += 40064;
    const size_t CSR_OFF = o; o += 680064;
    const size_t CSD_OFF = o; o += 680064;
    if (ws_size < o) return;

    u16*      A1   = (u16*)(ws + A1_OFF);
    unsigned* A2   = (unsigned*)(ws + A2_OFF);
    u16*      B2t  = (u16*)(ws + B2T_OFF);
    float*    wbuf = (float*)(ws + WB_OFF);
    u16*      H    = (u16*)(ws + H_OFF);
    u16*      B1t  = (u16*)(ws + B1T_OFF);
    float*    aS   = (float*)(ws + AS_OFF);
    float*    aD   = (float*)(ws + AD_OFF);
    int*      deg  = (int*)(ws + DEG_OFF);
    int*      offp = (int*)(ws + OFF_OFF);
    int*      cur  = (int*)(ws + CUR_OFF);
    int*      csr  = (int*)(ws + CSR_OFF);
    int*      csd  = (int*)(ws + CSD_OFF);

    // CSR build
    hipMemsetAsync(deg, 0, NN * sizeof(int), stream);
    k_count<<<(ET + 255) / 256, 256, 0, stream>>>(ei, deg);
    k_scan<<<1, 256, 0, stream>>>(deg, offp, cur);
    k_scatter<<<(ET + 255) / 256, 256, 0, stream>>>(ei, cur, csr, csd);

    // layer 1
    k_conv_x<<<2048, 256, 0, stream>>>(x, (uint2*)A1);
    k_convT<<<dim3(K1PAD / 32, NH / 32), dim3(32, 8), 0, stream>>>(W1, B1t, FIN, NH, K1PAD);
    k_gemm<false><<<NWG, 256, 0, stream>>>(A1, B1t, H, K1PAD, K1PAD / 32);
    k_attn<<<2500, 256, 0, stream>>>(H, as1, ad1, aS, aD);
    k_edgew<<<(ET + 255) / 256, 256, 0, stream>>>(aS, aD, csr, csd, wbuf);
    k_agg<1><<<6256, 256, 0, stream>>>(H, wbuf, offp, csr, b1, A2);
    k_zpad<<<280, 256, 0, stream>>>(A2);

    // layer 2
    k_convT<<<dim3(NH / 32, NH / 32), dim3(32, 8), 0, stream>>>(W2, B2t, NH, NH, NH);
    k_gemm<true><<<NWG, 256, 0, stream>>>((u16*)A2, B2t, H, NH, NH / 32);
    k_attn<<<2500, 256, 0, stream>>>(H, as2, ad2, aS, aD);
    k_edgew<<<(ET + 255) / 256, 256, 0, stream>>>(aS, aD, csr, csd, wbuf);
    k_agg<2><<<6256, 256, 0, stream>>>(H, wbuf, offp, csr, b2, A2);
    k_final<<<(NN * 64 + 255) / 256, 256, 0, stream>>>(A2, b2, (float*)d_out);
}

// Round 7
// 327.112 us; speedup vs baseline: 1.3949x; 1.0458x over previous
//
#include <hip/hip_runtime.h>

typedef unsigned short u16;
typedef __attribute__((ext_vector_type(8))) short bf16x8;
typedef __attribute__((ext_vector_type(4))) float f32x4;
typedef __attribute__((ext_vector_type(4))) unsigned u32x4;

#define NN    10000
#define EE    160000
#define ET    170000      // EE + NN self loops
#define FIN   2000
#define MPAD  10112       // 79*128
#define K1PAD 2048
#define NH    1280        // heads*channels
#define HEADS 10
#define NT    10          // N tiles (1280/128) == heads
#define NWG   790         // 79*10 gemm workgroups

__device__ __forceinline__ u16 f32_to_bf16(float f) {
    unsigned u = __float_as_uint(f);
    unsigned r = (u + 0x7fffu + ((u >> 16) & 1u)) >> 16;
    return (u16)r;
}
__device__ __forceinline__ float bf16lo(unsigned pv) { return __uint_as_float(pv << 16); }
__device__ __forceinline__ float bf16hi(unsigned pv) { return __uint_as_float(pv & 0xffff0000u); }

__device__ __forceinline__ void gload16(const u16* g, u16* l) {
    __builtin_amdgcn_global_load_lds(
        (const __attribute__((address_space(1))) void*)g,
        (__attribute__((address_space(3))) void*)l, 16, 0, 0);
}

// ---------------- conversion kernels ----------------

__global__ __launch_bounds__(256) void k_conv_x(const float* __restrict__ x,
                                                uint2* __restrict__ A1) {
    const int total = MPAD * (K1PAD / 4);
    for (int idx = blockIdx.x * 256 + threadIdx.x; idx < total; idx += gridDim.x * 256) {
        int r = idx >> 9;
        int c = (idx & 511) << 2;
        float4 v = make_float4(0.f, 0.f, 0.f, 0.f);
        if (r < NN && c < FIN) v = *(const float4*)(x + (size_t)r * FIN + c);
        uint2 p;
        p.x = (unsigned)f32_to_bf16(v.x) | ((unsigned)f32_to_bf16(v.y) << 16);
        p.y = (unsigned)f32_to_bf16(v.z) | ((unsigned)f32_to_bf16(v.w) << 16);
        A1[idx] = p;
    }
}

__global__ __launch_bounds__(256) void k_convT(const float* __restrict__ W,
                                               u16* __restrict__ Bt,
                                               int K, int Nn, int Kpad) {
    __shared__ float tile[32][33];
    int k0 = blockIdx.x * 32, n0 = blockIdx.y * 32;
    int tx = threadIdx.x, ty = threadIdx.y;   // (32,8)
    #pragma unroll
    for (int i = 0; i < 32; i += 8) {
        int k = k0 + ty + i;
        tile[ty + i][tx] = (k < K) ? W[(size_t)k * Nn + n0 + tx] : 0.f;
    }
    __syncthreads();
    #pragma unroll
    for (int i = 0; i < 32; i += 8) {
        int n = n0 + ty + i, k = k0 + tx;
        Bt[(size_t)n * Kpad + k] = f32_to_bf16(tile[tx][ty + i]);
    }
}

// ---------------- GEMM -> head-major C [10][MPAD][128] ----------------
// 128x128 tile, BK=32, TRIPLE-buffered 48KB LDS, prefetch distance 2 with
// counted vmcnt(4): tile kt's 4 loads/thread must land; kt+1's stay in flight
// across the barrier (never drain to 0 mid-loop). XCD-bijective swizzle.

template <bool AHM>
__global__ __launch_bounds__(256) void k_gemm(const u16* __restrict__ A,
                                              const u16* __restrict__ Bt,
                                              u16* __restrict__ Chm,
                                              const int Kpad, const int kTiles) {
    __shared__ __attribute__((aligned(16))) u16 S[24576];   // 3 x (A 8KB + B 8KB)
    const int bid = blockIdx.x;
    const int xcd = bid & 7, idx = bid >> 3;
    const int q = NWG >> 3, r = NWG & 7;
    const int L = (xcd < r) ? (xcd * (q + 1) + idx)
                            : (r * (q + 1) + (xcd - r) * q + idx);
    const size_t m0 = (size_t)(L / NT) * 128, n0 = (size_t)(L % NT) * 128;

    const int t = threadIdx.x;
    const int lane = t & 63;
    const int wave = t >> 6;
    const int wr = wave >> 1, wc = wave & 1;

    f32x4 acc[4][4] = {};

    const int srow = t >> 2;
    const int klocal = (((t & 3) ^ ((t >> 3) & 3)) << 3);
    const u16* aRow = AHM ? (A + (m0 + srow) * 128 + klocal)
                          : (A + (m0 + srow) * (size_t)Kpad + klocal);
    const u16* bRow = Bt + (n0 + srow) * (size_t)Kpad + klocal;

#define STAGE(kt_, bufb_) do {                                                   \
        char* db = (char*)S + (bufb_) + wave * 1024;                             \
        const u16* aP;                                                           \
        if (AHM) aP = aRow + (size_t)((kt_) >> 2) * (MPAD << 7) + ((kt_) & 3) * 32; \
        else     aP = aRow + (size_t)(kt_) * 32;                                 \
        const u16* bP = bRow + (size_t)(kt_) * 32;                               \
        const size_t aStep = AHM ? (size_t)64 * 128 : (size_t)64 * Kpad;         \
        gload16(aP,                 (u16*)(db));                                 \
        gload16(aP + aStep,         (u16*)(db + 4096));                          \
        gload16(bP,                 (u16*)(db + 8192));                          \
        gload16(bP + 64 * (size_t)Kpad, (u16*)(db + 12288));                     \
    } while (0)

    STAGE(0, 0);
    if (kTiles > 1) STAGE(1, 16384);

    const int rl = lane & 15;
    const int pa = ((lane >> 4) ^ ((rl >> 1) & 3)) << 4;
    const int aBase = (wr * 64 + rl) * 64 + pa;
    const int bBase = 8192 + (wc * 64 + rl) * 64 + pa;
    const char* Sb = (const char*)S;

    int cur = 0;                        // byte offset of current buffer
    for (int kt = 0; kt < kTiles; ++kt) {
        if (kt + 1 < kTiles) asm volatile("s_waitcnt vmcnt(4)" ::: "memory");
        else                 asm volatile("s_waitcnt vmcnt(0)" ::: "memory");
        __builtin_amdgcn_s_barrier();
        if (kt + 2 < kTiles) {
            int sb = cur + 32768; if (sb >= 49152) sb -= 49152;   // (kt+2)%3 buffer
            STAGE(kt + 2, sb);
        }
        bf16x8 af[4], bfr[4];
        #pragma unroll
        for (int mf = 0; mf < 4; ++mf)
            af[mf] = *(const bf16x8*)(Sb + cur + aBase + mf * 1024);
        #pragma unroll
        for (int nf = 0; nf < 4; ++nf)
            bfr[nf] = *(const bf16x8*)(Sb + cur + bBase + nf * 1024);
        #pragma unroll
        for (int mf = 0; mf < 4; ++mf)
            #pragma unroll
            for (int nf = 0; nf < 4; ++nf)
                acc[mf][nf] = __builtin_amdgcn_mfma_f32_16x16x32_bf16(
                    af[mf], bfr[nf], acc[mf][nf], 0, 0, 0);
        cur += 16384; if (cur >= 49152) cur = 0;
    }
#undef STAGE

    u16* Cb = Chm + (size_t)(n0 >> 7) * (MPAD << 7);
    #pragma unroll
    for (int mf = 0; mf < 4; ++mf)
        #pragma unroll
        for (int i = 0; i < 4; ++i) {
            size_t row = m0 + wr * 64 + mf * 16 + (lane >> 4) * 4 + i;
            u16* crow = Cb + row * 128 + wc * 64 + (lane & 15);
            #pragma unroll
            for (int nf = 0; nf < 4; ++nf)
                crow[nf * 16] = f32_to_bf16(acc[mf][nf][i]);
        }
}

// ---------------- attention coefficients: a_src/a_dst [10000][10] ----------------
__global__ __launch_bounds__(256) void k_attn(const u16* __restrict__ Hhm,
                                              const float* __restrict__ att_s,
                                              const float* __restrict__ att_d,
                                              float* __restrict__ a_src,
                                              float* __restrict__ a_dst) {
    const int lane = threadIdx.x & 63;
    const int n = blockIdx.x * 4 + (threadIdx.x >> 6);
    if (n >= NN) return;
    const unsigned* Hd = (const unsigned*)Hhm;
    #pragma unroll
    for (int h = 0; h < HEADS; ++h) {
        unsigned pv = Hd[((size_t)h * MPAD + n) * 64 + lane];
        float v0 = bf16lo(pv), v1 = bf16hi(pv);
        int c = h * 128 + lane * 2;
        float s = v0 * att_s[c] + v1 * att_s[c + 1];
        float d = v0 * att_d[c] + v1 * att_d[c + 1];
        #pragma unroll
        for (int o = 32; o; o >>= 1) { s += __shfl_xor(s, o); d += __shfl_xor(d, o); }
        if (lane == 0) { a_src[n * HEADS + h] = s; a_dst[n * HEADS + h] = d; }
    }
}

// ---------------- CSR build ----------------
__global__ void k_count(const int* __restrict__ ei, int* __restrict__ deg) {
    int e = blockIdx.x * blockDim.x + threadIdx.x;
    if (e >= ET) return;
    int d = (e < EE) ? ei[EE + e] : (e - EE);
    atomicAdd(&deg[d], 1);
}

__global__ __launch_bounds__(256) void k_scan(const int* __restrict__ deg,
                                              int* __restrict__ off,
                                              int* __restrict__ cursor) {
    __shared__ int wt[4];
    const int t = threadIdx.x, lane = t & 63, w = t >> 6;
    const int lo = t * 40;
    const int hi = (lo + 40 < NN) ? lo + 40 : NN;
    int s = 0;
    for (int i = lo; i < hi; ++i) s += deg[i];
    int x = s;
    #pragma unroll
    for (int o = 1; o < 64; o <<= 1) { int y = __shfl_up(x, o); if (lane >= o) x += y; }
    if (lane == 63) wt[w] = x;
    __syncthreads();
    int wp = 0;
    for (int k = 0; k < w; ++k) wp += wt[k];
    int run = wp + x - s;
    for (int i = lo; i < hi; ++i) { off[i] = run; cursor[i] = run; run += deg[i]; }
    if (t == 255) off[NN] = wp + x;
}

__global__ void k_scatter(const int* __restrict__ ei, int* __restrict__ cursor,
                          int* __restrict__ csr_src, int* __restrict__ csr_dst) {
    int e = blockIdx.x * blockDim.x + threadIdx.x;
    if (e >= ET) return;
    int s = (e < EE) ? ei[e] : (e - EE);
    int d = (e < EE) ? ei[EE + e] : (e - EE);
    int pos = atomicAdd(&cursor[d], 1);
    csr_src[pos] = s;
    csr_dst[pos] = d;
}

// ---------------- edge weights: wbuf[h][i] = exp(leaky(a_src[s][h]+a_dst[d][h])) ---
__global__ __launch_bounds__(256) void k_edgew(const float* __restrict__ a_src,
                                               const float* __restrict__ a_dst,
                                               const int* __restrict__ csr_s,
                                               const int* __restrict__ csr_d,
                                               float* __restrict__ wbuf) {
    int i = blockIdx.x * 256 + threadIdx.x;
    if (i >= ET) return;
    const int s = csr_s[i], d = csr_d[i];
    const float* ps = a_src + (size_t)s * HEADS;
    const float* pd = a_dst + (size_t)d * HEADS;
    #pragma unroll
    for (int h = 0; h < HEADS; ++h) {
        float e = ps[h] + pd[h];
        e = (e >= 0.f) ? e : 0.2f * e;
        wbuf[(size_t)h * ET + i] = __expf(e);
    }
}

// ---------------- head-split aggregate: wave = (head, 4 nodes) -------------------
template <int LAYER>
__global__ __launch_bounds__(256) void k_agg(const u16* __restrict__ Hhm,
                                             const float* __restrict__ wbuf,
                                             const int* __restrict__ off,
                                             const int* __restrict__ csr,
                                             const float* __restrict__ bias,
                                             unsigned* __restrict__ outp) {
    const int bid = blockIdx.x;
    const int xcd = bid & 7, slot = bid >> 3;
    const int wv = threadIdx.x >> 6, lane = threadIdx.x & 63;
    const int u = slot * 4 + wv;               // [0, 3128)
    if (u >= 3125) return;
    int h, qd;
    if (u < 2500) { h = xcd; qd = u; }
    else {
        int qg = xcd * 625 + (u - 2500);       // [0, 5000)
        h = 8 + (qg >= 2500);
        qd = (qg >= 2500) ? qg - 2500 : qg;
    }
    const int g = lane >> 4, l = lane & 15;
    const int n = qd * 4 + g;
    const int beg = off[n], end = off[n + 1];
    const u16* Hh = Hhm + (size_t)h * (MPAD * 128);
    const float* wp = wbuf + (size_t)h * ET;

    float acc[8] = {};
    float den = 0.f;
    int i = beg;
    for (; i + 1 < end; i += 2) {
        const int s0 = csr[i], s1 = csr[i + 1];
        const float w0 = wp[i], w1 = wp[i + 1];
        const u32x4 v0 = *(const u32x4*)(Hh + (size_t)s0 * 128 + l * 8);
        const u32x4 v1 = *(const u32x4*)(Hh + (size_t)s1 * 128 + l * 8);
        den += w0 + w1;
        #pragma unroll
        for (int j = 0; j < 4; ++j) {
            acc[2 * j]     = fmaf(bf16lo(v0[j]), w0, acc[2 * j]);
            acc[2 * j + 1] = fmaf(bf16hi(v0[j]), w0, acc[2 * j + 1]);
            acc[2 * j]     = fmaf(bf16lo(v1[j]), w1, acc[2 * j]);
            acc[2 * j + 1] = fmaf(bf16hi(v1[j]), w1, acc[2 * j + 1]);
        }
    }
    if (i < end) {
        const int s0 = csr[i];
        const float w0 = wp[i];
        const u32x4 v0 = *(const u32x4*)(Hh + (size_t)s0 * 128 + l * 8);
        den += w0;
        #pragma unroll
        for (int j = 0; j < 4; ++j) {
            acc[2 * j]     = fmaf(bf16lo(v0[j]), w0, acc[2 * j]);
            acc[2 * j + 1] = fmaf(bf16hi(v0[j]), w0, acc[2 * j + 1]);
        }
    }
    const float si = 1.f / (den + 1e-16f);

    u32x4 pk;
    if (LAYER == 1) {
        const int c = h * 128 + l * 8;
        #pragma unroll
        for (int j = 0; j < 4; ++j) {
            float v0 = fmaxf(fmaf(acc[2 * j],     si, bias[c + 2 * j]),     0.f);
            float v1 = fmaxf(fmaf(acc[2 * j + 1], si, bias[c + 2 * j + 1]), 0.f);
            pk[j] = (unsigned)f32_to_bf16(v0) | ((unsigned)f32_to_bf16(v1) << 16);
        }
    } else {
        #pragma unroll
        for (int j = 0; j < 4; ++j) {
            pk[j] = (unsigned)f32_to_bf16(acc[2 * j] * si)
                  | ((unsigned)f32_to_bf16(acc[2 * j + 1] * si) << 16);
        }
    }
    *(u32x4*)(outp + (size_t)h * (MPAD * 64) + (size_t)n * 64 + l * 4) = pk;
}

// zero pad rows NN..MPAD-1 of head-major A2 (10 slices)
__global__ __launch_bounds__(256) void k_zpad(unsigned* __restrict__ A2) {
    int idx = blockIdx.x * 256 + threadIdx.x;       // 10*112*64 = 71680 dwords
    if (idx >= 10 * 112 * 64) return;
    int h = idx / 7168, r = idx - h * 7168;
    int row = NN + (r >> 6), dw = r & 63;
    A2[((size_t)h * MPAD + row) * 64 + dw] = 0u;
}

// final: out[n][c] = relu(0.1 * sum_h Z[h][n][c] + b2[c])
__global__ __launch_bounds__(256) void k_final(const unsigned* __restrict__ Z,
                                               const float* __restrict__ b2,
                                               float* __restrict__ out) {
    int t = blockIdx.x * 256 + threadIdx.x;         // NN*64 dword slots
    if (t >= NN * 64) return;
    int n = t >> 6, d = t & 63;
    float s0 = 0.f, s1 = 0.f;
    #pragma unroll
    for (int h = 0; h < HEADS; ++h) {
        unsigned pv = Z[(size_t)h * (MPAD * 64) + (size_t)n * 64 + d];
        s0 += bf16lo(pv);
        s1 += bf16hi(pv);
    }
    float2 z;
    z.x = fmaxf(fmaf(s0, 0.1f, b2[2 * d]),     0.f);
    z.y = fmaxf(fmaf(s1, 0.1f, b2[2 * d + 1]), 0.f);
    *(float2*)(out + (size_t)n * 128 + 2 * d) = z;
}

// ---------------- host ----------------
extern "C" void kernel_launch(void* const* d_in, const int* in_sizes, int n_in,
                              void* d_out, int out_size, void* d_ws, size_t ws_size,
                              hipStream_t stream) {
    const float* x   = (const float*)d_in[0];
    const int*   ei  = (const int*)  d_in[1];
    const float* W1  = (const float*)d_in[2];
    const float* as1 = (const float*)d_in[3];
    const float* ad1 = (const float*)d_in[4];
    const float* b1  = (const float*)d_in[5];
    const float* W2  = (const float*)d_in[6];
    const float* as2 = (const float*)d_in[7];
    const float* ad2 = (const float*)d_in[8];
    const float* b2  = (const float*)d_in[9];

    char* ws = (char*)d_ws;
    const size_t A1_OFF  = 0;                       // A1 [MPAD][2048] bf16 (41.4MB)
    const size_t A2_OFF  = 0;                       // A2hm / Z [10][MPAD][128] bf16
    const size_t B2T_OFF = (size_t)MPAD * NH * 2;   // 25,886,720 (+3.28MB)
    const size_t WB_OFF  = B2T_OFF + (size_t)NH * NH * 2;   // 29,163,520 (+6.8MB)
    const size_t H_OFF   = (size_t)MPAD * K1PAD * 2;        // 41,418,752
    const size_t B1T_OFF = H_OFF + (size_t)MPAD * NH * 2;   // 67,305,472
    size_t o = B1T_OFF + (size_t)NH * K1PAD * 2;
    const size_t AS_OFF  = o; o += 400128;
    const size_t AD_OFF  = o; o += 400128;
    const size_t DEG_OFF = o; o += 40064;
    const size_t OFF_OFF = o; o += 40064;
    const size_t CUR_OFF = o; o += 40064;
    const size_t CSR_OFF = o; o += 680064;
    const size_t CSD_OFF = o; o += 680064;
    if (ws_size < o) return;

    u16*      A1   = (u16*)(ws + A1_OFF);
    unsigned* A2   = (unsigned*)(ws + A2_OFF);
    u16*      B2t  = (u16*)(ws + B2T_OFF);
    float*    wbuf = (float*)(ws + WB_OFF);
    u16*      H    = (u16*)(ws + H_OFF);
    u16*      B1t  = (u16*)(ws + B1T_OFF);
    float*    aS   = (float*)(ws + AS_OFF);
    float*    aD   = (float*)(ws + AD_OFF);
    int*      deg  = (int*)(ws + DEG_OFF);
    int*      offp = (int*)(ws + OFF_OFF);
    int*      cur  = (int*)(ws + CUR_OFF);
    int*      csr  = (int*)(ws + CSR_OFF);
    int*      csd  = (int*)(ws + CSD_OFF);

    // CSR build
    hipMemsetAsync(deg, 0, NN * sizeof(int), stream);
    k_count<<<(ET + 255) / 256, 256, 0, stream>>>(ei, deg);
    k_scan<<<1, 256, 0, stream>>>(deg, offp, cur);
    k_scatter<<<(ET + 255) / 256, 256, 0, stream>>>(ei, cur, csr, csd);

    // layer 1
    k_conv_x<<<2048, 256, 0, stream>>>(x, (uint2*)A1);
    k_convT<<<dim3(K1PAD / 32, NH / 32), dim3(32, 8), 0, stream>>>(W1, B1t, FIN, NH, K1PAD);
    k_gemm<false><<<NWG, 256, 0, stream>>>(A1, B1t, H, K1PAD, K1PAD / 32);
    k_attn<<<2500, 256, 0, stream>>>(H, as1, ad1, aS, aD);
    k_edgew<<<(ET + 255) / 256, 256, 0, stream>>>(aS, aD, csr, csd, wbuf);
    k_agg<1><<<6256, 256, 0, stream>>>(H, wbuf, offp, csr, b1, A2);
    k_zpad<<<280, 256, 0, stream>>>(A2);

    // layer 2
    k_convT<<<dim3(NH / 32, NH / 32), dim3(32, 8), 0, stream>>>(W2, B2t, NH, NH, NH);
    k_gemm<true><<<NWG, 256, 0, stream>>>((u16*)A2, B2t, H, NH, NH / 32);
    k_attn<<<2500, 256, 0, stream>>>(H, as2, ad2, aS, aD);
    k_edgew<<<(ET + 255) / 256, 256, 0, stream>>>(aS, aD, csr, csd, wbuf);
    k_agg<2><<<6256, 256, 0, stream>>>(H, wbuf, offp, csr, b2, A2);
    k_final<<<(NN * 64 + 255) / 256, 256, 0, stream>>>(A2, b2, (float*)d_out);
}

// Round 8
// 327.011 us; speedup vs baseline: 1.3954x; 1.0003x over previous
//
#include <hip/hip_runtime.h>

typedef unsigned short u16;
typedef __attribute__((ext_vector_type(8))) short bf16x8;
typedef __attribute__((ext_vector_type(4))) float f32x4;
typedef __attribute__((ext_vector_type(4))) unsigned u32x4;

#define NN    10000
#define EE    160000
#define ET    170000      // EE + NN self loops
#define FIN   2000
#define MPAD  10112       // 79*128
#define K1PAD 2048
#define NH    1280        // heads*channels
#define HEADS 10
#define NT    10          // N tiles (1280/128) == heads
#define NWG   790         // 79*10 gemm workgroups

__device__ __forceinline__ u16 f32_to_bf16(float f) {
    unsigned u = __float_as_uint(f);
    unsigned r = (u + 0x7fffu + ((u >> 16) & 1u)) >> 16;
    return (u16)r;
}
__device__ __forceinline__ float bf16lo(unsigned pv) { return __uint_as_float(pv << 16); }
__device__ __forceinline__ float bf16hi(unsigned pv) { return __uint_as_float(pv & 0xffff0000u); }

__device__ __forceinline__ void gload16(const u16* g, u16* l) {
    __builtin_amdgcn_global_load_lds(
        (const __attribute__((address_space(1))) void*)g,
        (__attribute__((address_space(3))) void*)l, 16, 0, 0);
}

// ---------------- conversion kernels ----------------

__global__ __launch_bounds__(256) void k_conv_x(const float* __restrict__ x,
                                                uint2* __restrict__ A1) {
    const int total = MPAD * (K1PAD / 4);
    for (int idx = blockIdx.x * 256 + threadIdx.x; idx < total; idx += gridDim.x * 256) {
        int r = idx >> 9;
        int c = (idx & 511) << 2;
        float4 v = make_float4(0.f, 0.f, 0.f, 0.f);
        if (r < NN && c < FIN) v = *(const float4*)(x + (size_t)r * FIN + c);
        uint2 p;
        p.x = (unsigned)f32_to_bf16(v.x) | ((unsigned)f32_to_bf16(v.y) << 16);
        p.y = (unsigned)f32_to_bf16(v.z) | ((unsigned)f32_to_bf16(v.w) << 16);
        A1[idx] = p;
    }
}

__global__ __launch_bounds__(256) void k_convT(const float* __restrict__ W,
                                               u16* __restrict__ Bt,
                                               int K, int Nn, int Kpad) {
    __shared__ float tile[32][33];
    int k0 = blockIdx.x * 32, n0 = blockIdx.y * 32;
    int tx = threadIdx.x, ty = threadIdx.y;   // (32,8)
    #pragma unroll
    for (int i = 0; i < 32; i += 8) {
        int k = k0 + ty + i;
        tile[ty + i][tx] = (k < K) ? W[(size_t)k * Nn + n0 + tx] : 0.f;
    }
    __syncthreads();
    #pragma unroll
    for (int i = 0; i < 32; i += 8) {
        int n = n0 + ty + i, k = k0 + tx;
        Bt[(size_t)n * Kpad + k] = f32_to_bf16(tile[tx][ty + i]);
    }
}

// ---------------- GEMM -> head-major C [10][MPAD][128] ----------------
// 128x128 tile, BK=32, triple-buffered 48KB LDS, global prefetch distance 3,
// register fragment double-buffer: ds_reads for tile kt+1 issue before tile kt's
// MFMA cluster -> MFMA never waits same-iter LDS latency. Requires kTiles >= 3 even.

template <bool AHM>
__global__ __launch_bounds__(256) void k_gemm(const u16* __restrict__ A,
                                              const u16* __restrict__ Bt,
                                              u16* __restrict__ Chm,
                                              const int Kpad, const int kTiles) {
    __shared__ __attribute__((aligned(16))) u16 S[24576];   // 3 x (A 8KB + B 8KB)
    const int bid = blockIdx.x;
    const int xcd = bid & 7, idx = bid >> 3;
    const int q = NWG >> 3, r = NWG & 7;
    const int L = (xcd < r) ? (xcd * (q + 1) + idx)
                            : (r * (q + 1) + (xcd - r) * q + idx);
    const size_t m0 = (size_t)(L / NT) * 128, n0 = (size_t)(L % NT) * 128;

    const int t = threadIdx.x;
    const int lane = t & 63;
    const int wave = t >> 6;
    const int wr = wave >> 1, wc = wave & 1;

    f32x4 acc[4][4] = {};

    const int srow = t >> 2;
    const int klocal = (((t & 3) ^ ((t >> 3) & 3)) << 3);
    const u16* aRow = AHM ? (A + (m0 + srow) * 128 + klocal)
                          : (A + (m0 + srow) * (size_t)Kpad + klocal);
    const u16* bRow = Bt + (n0 + srow) * (size_t)Kpad + klocal;

#define STAGE(kt_, bufb_) do {                                                   \
        char* db = (char*)S + (bufb_) + wave * 1024;                             \
        const u16* aP;                                                           \
        if (AHM) aP = aRow + (size_t)((kt_) >> 2) * (MPAD << 7) + ((kt_) & 3) * 32; \
        else     aP = aRow + (size_t)(kt_) * 32;                                 \
        const u16* bP = bRow + (size_t)(kt_) * 32;                               \
        const size_t aStep = AHM ? (size_t)64 * 128 : (size_t)64 * Kpad;         \
        gload16(aP,                 (u16*)(db));                                 \
        gload16(aP + aStep,         (u16*)(db + 4096));                          \
        gload16(bP,                 (u16*)(db + 8192));                          \
        gload16(bP + 64 * (size_t)Kpad, (u16*)(db + 12288));                     \
    } while (0)

#define LOADFRAG(fa_, fb_, bo_) do {                                             \
        _Pragma("unroll")                                                        \
        for (int mf_ = 0; mf_ < 4; ++mf_)                                        \
            fa_[mf_] = *(const bf16x8*)(Sb + (bo_) + aBase + mf_ * 1024);        \
        _Pragma("unroll")                                                        \
        for (int nf_ = 0; nf_ < 4; ++nf_)                                        \
            fb_[nf_] = *(const bf16x8*)(Sb + (bo_) + bBase + nf_ * 1024);        \
    } while (0)

#define MFMA16(fa_, fb_) do {                                                    \
        __builtin_amdgcn_s_setprio(1);                                           \
        _Pragma("unroll")                                                        \
        for (int mf_ = 0; mf_ < 4; ++mf_)                                        \
            _Pragma("unroll")                                                    \
            for (int nf_ = 0; nf_ < 4; ++nf_)                                    \
                acc[mf_][nf_] = __builtin_amdgcn_mfma_f32_16x16x32_bf16(         \
                    fa_[mf_], fb_[nf_], acc[mf_][nf_], 0, 0, 0);                 \
        __builtin_amdgcn_s_setprio(0);                                           \
    } while (0)

    const int rl = lane & 15;
    const int pa = ((lane >> 4) ^ ((rl >> 1) & 3)) << 4;
    const int aBase = (wr * 64 + rl) * 64 + pa;
    const int bBase = 8192 + (wc * 64 + rl) * 64 + pa;
    const char* Sb = (const char*)S;

    STAGE(0, 0);
    STAGE(1, 16384);
    STAGE(2, 32768);
    asm volatile("s_waitcnt vmcnt(8)" ::: "memory");   // stage 0 landed (mine)
    __builtin_amdgcn_s_barrier();                      // everyone's stage 0 landed

    bf16x8 fa0[4], fb0[4], fa1[4], fb1[4];
    LOADFRAG(fa0, fb0, 0);                             // frag for kt=0

    int stb = 0;        // STAGE(kt+3) dest = buf[kt%3]
    int rdb = 16384;    // frag[kt+1] source = buf[(kt+1)%3]
    for (int kt = 0; kt < kTiles; kt += 2) {
        // ---- sub-iter kt: compute frag0, prefetch frag1 ----
        if (kt + 2 < kTiles) asm volatile("s_waitcnt vmcnt(4) lgkmcnt(0)" ::: "memory");
        else                 asm volatile("s_waitcnt vmcnt(0) lgkmcnt(0)" ::: "memory");
        __builtin_amdgcn_s_barrier();
        if (kt + 3 < kTiles) STAGE(kt + 3, stb);
        stb += 16384; if (stb >= 49152) stb = 0;
        LOADFRAG(fa1, fb1, rdb);                       // kt+1 < kTiles (even kTiles)
        rdb += 16384; if (rdb >= 49152) rdb = 0;
        MFMA16(fa0, fb0);
        // ---- sub-iter kt+1: compute frag1, prefetch frag0 ----
        if (kt + 3 < kTiles) asm volatile("s_waitcnt vmcnt(4) lgkmcnt(0)" ::: "memory");
        else                 asm volatile("s_waitcnt vmcnt(0) lgkmcnt(0)" ::: "memory");
        __builtin_amdgcn_s_barrier();
        if (kt + 4 < kTiles) STAGE(kt + 4, stb);
        stb += 16384; if (stb >= 49152) stb = 0;
        if (kt + 2 < kTiles) LOADFRAG(fa0, fb0, rdb);
        rdb += 16384; if (rdb >= 49152) rdb = 0;
        MFMA16(fa1, fb1);
    }
#undef STAGE
#undef LOADFRAG
#undef MFMA16

    u16* Cb = Chm + (size_t)(n0 >> 7) * (MPAD << 7);
    #pragma unroll
    for (int mf = 0; mf < 4; ++mf)
        #pragma unroll
        for (int i = 0; i < 4; ++i) {
            size_t row = m0 + wr * 64 + mf * 16 + (lane >> 4) * 4 + i;
            u16* crow = Cb + row * 128 + wc * 64 + (lane & 15);
            #pragma unroll
            for (int nf = 0; nf < 4; ++nf)
                crow[nf * 16] = f32_to_bf16(acc[mf][nf][i]);
        }
}

// ---------------- attention coefficients: a_src/a_dst [10000][10] ----------------
__global__ __launch_bounds__(256) void k_attn(const u16* __restrict__ Hhm,
                                              const float* __restrict__ att_s,
                                              const float* __restrict__ att_d,
                                              float* __restrict__ a_src,
                                              float* __restrict__ a_dst) {
    const int lane = threadIdx.x & 63;
    const int n = blockIdx.x * 4 + (threadIdx.x >> 6);
    if (n >= NN) return;
    const unsigned* Hd = (const unsigned*)Hhm;
    #pragma unroll
    for (int h = 0; h < HEADS; ++h) {
        unsigned pv = Hd[((size_t)h * MPAD + n) * 64 + lane];
        float v0 = bf16lo(pv), v1 = bf16hi(pv);
        int c = h * 128 + lane * 2;
        float s = v0 * att_s[c] + v1 * att_s[c + 1];
        float d = v0 * att_d[c] + v1 * att_d[c + 1];
        #pragma unroll
        for (int o = 32; o; o >>= 1) { s += __shfl_xor(s, o); d += __shfl_xor(d, o); }
        if (lane == 0) { a_src[n * HEADS + h] = s; a_dst[n * HEADS + h] = d; }
    }
}

// ---------------- CSR build ----------------
__global__ void k_count(const int* __restrict__ ei, int* __restrict__ deg) {
    int e = blockIdx.x * blockDim.x + threadIdx.x;
    if (e >= ET) return;
    int d = (e < EE) ? ei[EE + e] : (e - EE);
    atomicAdd(&deg[d], 1);
}

__global__ __launch_bounds__(256) void k_scan(const int* __restrict__ deg,
                                              int* __restrict__ off,
                                              int* __restrict__ cursor) {
    __shared__ int wt[4];
    const int t = threadIdx.x, lane = t & 63, w = t >> 6;
    const int lo = t * 40;
    const int hi = (lo + 40 < NN) ? lo + 40 : NN;
    int s = 0;
    for (int i = lo; i < hi; ++i) s += deg[i];
    int x = s;
    #pragma unroll
    for (int o = 1; o < 64; o <<= 1) { int y = __shfl_up(x, o); if (lane >= o) x += y; }
    if (lane == 63) wt[w] = x;
    __syncthreads();
    int wp = 0;
    for (int k = 0; k < w; ++k) wp += wt[k];
    int run = wp + x - s;
    for (int i = lo; i < hi; ++i) { off[i] = run; cursor[i] = run; run += deg[i]; }
    if (t == 255) off[NN] = wp + x;
}

__global__ void k_scatter(const int* __restrict__ ei, int* __restrict__ cursor,
                          int* __restrict__ csr_src, int* __restrict__ csr_dst) {
    int e = blockIdx.x * blockDim.x + threadIdx.x;
    if (e >= ET) return;
    int s = (e < EE) ? ei[e] : (e - EE);
    int d = (e < EE) ? ei[EE + e] : (e - EE);
    int pos = atomicAdd(&cursor[d], 1);
    csr_src[pos] = s;
    csr_dst[pos] = d;
}

// ---------------- edge weights: wbuf[h][i] = exp(leaky(a_src[s][h]+a_dst[d][h])) ---
__global__ __launch_bounds__(256) void k_edgew(const float* __restrict__ a_src,
                                               const float* __restrict__ a_dst,
                                               const int* __restrict__ csr_s,
                                               const int* __restrict__ csr_d,
                                               float* __restrict__ wbuf) {
    int i = blockIdx.x * 256 + threadIdx.x;
    if (i >= ET) return;
    const int s = csr_s[i], d = csr_d[i];
    const float* ps = a_src + (size_t)s * HEADS;
    const float* pd = a_dst + (size_t)d * HEADS;
    #pragma unroll
    for (int h = 0; h < HEADS; ++h) {
        float e = ps[h] + pd[h];
        e = (e >= 0.f) ? e : 0.2f * e;
        wbuf[(size_t)h * ET + i] = __expf(e);
    }
}

// ---------------- head-split aggregate: wave = (head, 4 nodes) -------------------
template <int LAYER>
__global__ __launch_bounds__(256) void k_agg(const u16* __restrict__ Hhm,
                                             const float* __restrict__ wbuf,
                                             const int* __restrict__ off,
                                             const int* __restrict__ csr,
                                             const float* __restrict__ bias,
                                             unsigned* __restrict__ outp) {
    const int bid = blockIdx.x;
    const int xcd = bid & 7, slot = bid >> 3;
    const int wv = threadIdx.x >> 6, lane = threadIdx.x & 63;
    const int u = slot * 4 + wv;               // [0, 3128)
    if (u >= 3125) return;
    int h, qd;
    if (u < 2500) { h = xcd; qd = u; }
    else {
        int qg = xcd * 625 + (u - 2500);       // [0, 5000)
        h = 8 + (qg >= 2500);
        qd = (qg >= 2500) ? qg - 2500 : qg;
    }
    const int g = lane >> 4, l = lane & 15;
    const int n = qd * 4 + g;
    const int beg = off[n], end = off[n + 1];
    const u16* Hh = Hhm + (size_t)h * (MPAD * 128);
    const float* wp = wbuf + (size_t)h * ET;

    float acc[8] = {};
    float den = 0.f;
    int i = beg;
    for (; i + 1 < end; i += 2) {
        const int s0 = csr[i], s1 = csr[i + 1];
        const float w0 = wp[i], w1 = wp[i + 1];
        const u32x4 v0 = *(const u32x4*)(Hh + (size_t)s0 * 128 + l * 8);
        const u32x4 v1 = *(const u32x4*)(Hh + (size_t)s1 * 128 + l * 8);
        den += w0 + w1;
        #pragma unroll
        for (int j = 0; j < 4; ++j) {
            acc[2 * j]     = fmaf(bf16lo(v0[j]), w0, acc[2 * j]);
            acc[2 * j + 1] = fmaf(bf16hi(v0[j]), w0, acc[2 * j + 1]);
            acc[2 * j]     = fmaf(bf16lo(v1[j]), w1, acc[2 * j]);
            acc[2 * j + 1] = fmaf(bf16hi(v1[j]), w1, acc[2 * j + 1]);
        }
    }
    if (i < end) {
        const int s0 = csr[i];
        const float w0 = wp[i];
        const u32x4 v0 = *(const u32x4*)(Hh + (size_t)s0 * 128 + l * 8);
        den += w0;
        #pragma unroll
        for (int j = 0; j < 4; ++j) {
            acc[2 * j]     = fmaf(bf16lo(v0[j]), w0, acc[2 * j]);
            acc[2 * j + 1] = fmaf(bf16hi(v0[j]), w0, acc[2 * j + 1]);
        }
    }
    const float si = 1.f / (den + 1e-16f);

    u32x4 pk;
    if (LAYER == 1) {
        const int c = h * 128 + l * 8;
        #pragma unroll
        for (int j = 0; j < 4; ++j) {
            float v0 = fmaxf(fmaf(acc[2 * j],     si, bias[c + 2 * j]),     0.f);
            float v1 = fmaxf(fmaf(acc[2 * j + 1], si, bias[c + 2 * j + 1]), 0.f);
            pk[j] = (unsigned)f32_to_bf16(v0) | ((unsigned)f32_to_bf16(v1) << 16);
        }
    } else {
        #pragma unroll
        for (int j = 0; j < 4; ++j) {
            pk[j] = (unsigned)f32_to_bf16(acc[2 * j] * si)
                  | ((unsigned)f32_to_bf16(acc[2 * j + 1] * si) << 16);
        }
    }
    *(u32x4*)(outp + (size_t)h * (MPAD * 64) + (size_t)n * 64 + l * 4) = pk;
}

// zero pad rows NN..MPAD-1 of head-major A2 (10 slices)
__global__ __launch_bounds__(256) void k_zpad(unsigned* __restrict__ A2) {
    int idx = blockIdx.x * 256 + threadIdx.x;       // 10*112*64 = 71680 dwords
    if (idx >= 10 * 112 * 64) return;
    int h = idx / 7168, r = idx - h * 7168;
    int row = NN + (r >> 6), dw = r & 63;
    A2[((size_t)h * MPAD + row) * 64 + dw] = 0u;
}

// final: out[n][c] = relu(0.1 * sum_h Z[h][n][c] + b2[c])
__global__ __launch_bounds__(256) void k_final(const unsigned* __restrict__ Z,
                                               const float* __restrict__ b2,
                                               float* __restrict__ out) {
    int t = blockIdx.x * 256 + threadIdx.x;         // NN*64 dword slots
    if (t >= NN * 64) return;
    int n = t >> 6, d = t & 63;
    float s0 = 0.f, s1 = 0.f;
    #pragma unroll
    for (int h = 0; h < HEADS; ++h) {
        unsigned pv = Z[(size_t)h * (MPAD * 64) + (size_t)n * 64 + d];
        s0 += bf16lo(pv);
        s1 += bf16hi(pv);
    }
    float2 z;
    z.x = fmaxf(fmaf(s0, 0.1f, b2[2 * d]),     0.f);
    z.y = fmaxf(fmaf(s1, 0.1f, b2[2 * d + 1]), 0.f);
    *(float2*)(out + (size_t)n * 128 + 2 * d) = z;
}

// ---------------- host ----------------
extern "C" void kernel_launch(void* const* d_in, const int* in_sizes, int n_in,
                              void* d_out, int out_size, void* d_ws, size_t ws_size,
                              hipStream_t stream) {
    const float* x   = (const float*)d_in[0];
    const int*   ei  = (const int*)  d_in[1];
    const float* W1  = (const float*)d_in[2];
    const float* as1 = (const float*)d_in[3];
    const float* ad1 = (const float*)d_in[4];
    const float* b1  = (const float*)d_in[5];
    const float* W2  = (const float*)d_in[6];
    const float* as2 = (const float*)d_in[7];
    const float* ad2 = (const float*)d_in[8];
    const float* b2  = (const float*)d_in[9];

    char* ws = (char*)d_ws;
    const size_t A1_OFF  = 0;                       // A1 [MPAD][2048] bf16 (41.4MB)
    const size_t A2_OFF  = 0;                       // A2hm / Z [10][MPAD][128] bf16
    const size_t B2T_OFF = (size_t)MPAD * NH * 2;   // 25,886,720 (+3.28MB)
    const size_t WB_OFF  = B2T_OFF + (size_t)NH * NH * 2;   // 29,163,520 (+6.8MB)
    const size_t H_OFF   = (size_t)MPAD * K1PAD * 2;        // 41,418,752
    const size_t B1T_OFF = H_OFF + (size_t)MPAD * NH * 2;   // 67,305,472
    size_t o = B1T_OFF + (size_t)NH * K1PAD * 2;
    const size_t AS_OFF  = o; o += 400128;
    const size_t AD_OFF  = o; o += 400128;
    const size_t DEG_OFF = o; o += 40064;
    const size_t OFF_OFF = o; o += 40064;
    const size_t CUR_OFF = o; o += 40064;
    const size_t CSR_OFF = o; o += 680064;
    const size_t CSD_OFF = o; o += 680064;
    if (ws_size < o) return;

    u16*      A1   = (u16*)(ws + A1_OFF);
    unsigned* A2   = (unsigned*)(ws + A2_OFF);
    u16*      B2t  = (u16*)(ws + B2T_OFF);
    float*    wbuf = (float*)(ws + WB_OFF);
    u16*      H    = (u16*)(ws + H_OFF);
    u16*      B1t  = (u16*)(ws + B1T_OFF);
    float*    aS   = (float*)(ws + AS_OFF);
    float*    aD   = (float*)(ws + AD_OFF);
    int*      deg  = (int*)(ws + DEG_OFF);
    int*      offp = (int*)(ws + OFF_OFF);
    int*      cur  = (int*)(ws + CUR_OFF);
    int*      csr  = (int*)(ws + CSR_OFF);
    int*      csd  = (int*)(ws + CSD_OFF);

    // CSR build
    hipMemsetAsync(deg, 0, NN * sizeof(int), stream);
    k_count<<<(ET + 255) / 256, 256, 0, stream>>>(ei, deg);
    k_scan<<<1, 256, 0, stream>>>(deg, offp, cur);
    k_scatter<<<(ET + 255) / 256, 256, 0, stream>>>(ei, cur, csr, csd);

    // layer 1
    k_conv_x<<<2048, 256, 0, stream>>>(x, (uint2*)A1);
    k_convT<<<dim3(K1PAD / 32, NH / 32), dim3(32, 8), 0, stream>>>(W1, B1t, FIN, NH, K1PAD);
    k_gemm<false><<<NWG, 256, 0, stream>>>(A1, B1t, H, K1PAD, K1PAD / 32);
    k_attn<<<2500, 256, 0, stream>>>(H, as1, ad1, aS, aD);
    k_edgew<<<(ET + 255) / 256, 256, 0, stream>>>(aS, aD, csr, csd, wbuf);
    k_agg<1><<<6256, 256, 0, stream>>>(H, wbuf, offp, csr, b1, A2);
    k_zpad<<<280, 256, 0, stream>>>(A2);

    // layer 2
    k_convT<<<dim3(NH / 32, NH / 32), dim3(32, 8), 0, stream>>>(W2, B2t, NH, NH, NH);
    k_gemm<true><<<NWG, 256, 0, stream>>>((u16*)A2, B2t, H, NH, NH / 32);
    k_attn<<<2500, 256, 0, stream>>>(H, as2, ad2, aS, aD);
    k_edgew<<<(ET + 255) / 256, 256, 0, stream>>>(aS, aD, csr, csd, wbuf);
    k_agg<2><<<6256, 256, 0, stream>>>(H, wbuf, offp, csr, b2, A2);
    k_final<<<(NN * 64 + 255) / 256, 256, 0, stream>>>(A2, b2, (float*)d_out);
}

// Round 9
// 303.470 us; speedup vs baseline: 1.5036x; 1.0776x over previous
//
#include <hip/hip_runtime.h>

typedef unsigned short u16;
typedef __attribute__((ext_vector_type(8))) short bf16x8;
typedef __attribute__((ext_vector_type(4))) float f32x4;
typedef __attribute__((ext_vector_type(4))) unsigned u32x4;

#define NN    10000
#define EE    160000
#define ET    170000      // EE + NN self loops
#define FIN   2000
#define MPAD  10112       // 79*128
#define K1PAD 2048
#define NH    1280        // heads*channels
#define HEADS 10
#define NT    10          // N tiles (1280/128) == heads
#define NWG   790         // 79*10 gemm workgroups

__device__ __forceinline__ u16 f32_to_bf16(float f) {
    unsigned u = __float_as_uint(f);
    unsigned r = (u + 0x7fffu + ((u >> 16) & 1u)) >> 16;
    return (u16)r;
}
__device__ __forceinline__ float bf16lo(unsigned pv) { return __uint_as_float(pv << 16); }
__device__ __forceinline__ float bf16hi(unsigned pv) { return __uint_as_float(pv & 0xffff0000u); }

__device__ __forceinline__ void gload16(const u16* g, u16* l) {
    __builtin_amdgcn_global_load_lds(
        (const __attribute__((address_space(1))) void*)g,
        (__attribute__((address_space(3))) void*)l, 16, 0, 0);
}

// ---------------- conversion kernels ----------------

__global__ __launch_bounds__(256) void k_conv_x(const float* __restrict__ x,
                                                uint2* __restrict__ A1) {
    const int total = MPAD * (K1PAD / 4);
    for (int idx = blockIdx.x * 256 + threadIdx.x; idx < total; idx += gridDim.x * 256) {
        int r = idx >> 9;
        int c = (idx & 511) << 2;
        float4 v = make_float4(0.f, 0.f, 0.f, 0.f);
        if (r < NN && c < FIN) v = *(const float4*)(x + (size_t)r * FIN + c);
        uint2 p;
        p.x = (unsigned)f32_to_bf16(v.x) | ((unsigned)f32_to_bf16(v.y) << 16);
        p.y = (unsigned)f32_to_bf16(v.z) | ((unsigned)f32_to_bf16(v.w) << 16);
        A1[idx] = p;
    }
}

__global__ __launch_bounds__(256) void k_convT(const float* __restrict__ W,
                                               u16* __restrict__ Bt,
                                               int K, int Nn, int Kpad) {
    __shared__ float tile[32][33];
    int k0 = blockIdx.x * 32, n0 = blockIdx.y * 32;
    int tx = threadIdx.x, ty = threadIdx.y;   // (32,8)
    #pragma unroll
    for (int i = 0; i < 32; i += 8) {
        int k = k0 + ty + i;
        tile[ty + i][tx] = (k < K) ? W[(size_t)k * Nn + n0 + tx] : 0.f;
    }
    __syncthreads();
    #pragma unroll
    for (int i = 0; i < 32; i += 8) {
        int n = n0 + ty + i, k = k0 + tx;
        Bt[(size_t)n * Kpad + k] = f32_to_bf16(tile[tx][ty + i]);
    }
}

// ---------------- GEMM -> head-major C [10][MPAD][128] ----------------
// 128x128 tile, BK=64, 8 waves (wave tile 64x32), double-buffered 64KB LDS.
// Round-3 proven schedule: wait vmcnt(0) -> barrier -> stage(kt+1) -> 32 MFMA.
// 2 blocks/CU x 8 waves = 16 waves/CU: TLP hides the barrier/vmcnt latency.
// LDS rows are 128B, chunk-XOR swizzle (phys16B = log ^ (row&7)) -> conflict-free.

template <bool AHM>
__global__ __launch_bounds__(512) void k_gemm(const u16* __restrict__ A,
                                              const u16* __restrict__ Bt,
                                              u16* __restrict__ Chm,
                                              const int Kpad, const int kTiles) {
    __shared__ __attribute__((aligned(16))) u16 S[32768];   // 2 x (A 16KB + B 16KB)
    const int bid = blockIdx.x;
    const int xcd = bid & 7, idx = bid >> 3;
    const int q = NWG >> 3, r = NWG & 7;
    const int L = (xcd < r) ? (xcd * (q + 1) + idx)
                            : (r * (q + 1) + (xcd - r) * q + idx);
    const size_t m0 = (size_t)(L / NT) * 128, n0 = (size_t)(L % NT) * 128;

    const int t = threadIdx.x;
    const int lane = t & 63;
    const int wave = t >> 6;              // 0..7
    const int wr = wave >> 2, wc = wave & 3;

    f32x4 acc[4][2] = {};

    // staging: thread t -> row srow = t>>3 (and +64), phys 16B chunk c = t&7,
    // source logical chunk = c ^ (srow&7). LDS dest is lane-linear: wave*1024 + lane*16.
    const int srow = t >> 3;
    const int klocal = (((t & 7) ^ ((t >> 3) & 7)) << 3);   // elems within BK=64
    const u16* aRow = AHM ? (A + (m0 + srow) * 128 + klocal)
                          : (A + (m0 + srow) * (size_t)Kpad + klocal);
    const u16* bRow = Bt + (n0 + srow) * (size_t)Kpad + klocal;
    const size_t aStep = AHM ? (size_t)64 * 128 : (size_t)64 * Kpad;
    const size_t bStep = (size_t)64 * Kpad;

#define STAGE(kt_, bufb_) do {                                                   \
        char* db = (char*)S + (bufb_) + wave * 1024;                             \
        const u16* aP;                                                           \
        if (AHM) aP = aRow + (size_t)((kt_) >> 1) * (MPAD << 7) + ((kt_) & 1) * 64; \
        else     aP = aRow + (size_t)(kt_) * 64;                                 \
        const u16* bP = bRow + (size_t)(kt_) * 64;                               \
        gload16(aP,         (u16*)(db));                                         \
        gload16(aP + aStep, (u16*)(db + 8192));                                  \
        gload16(bP,         (u16*)(db + 16384));                                 \
        gload16(bP + bStep, (u16*)(db + 24576));                                 \
    } while (0)

    STAGE(0, 0);

    const int rl = lane & 15;
    const int kchunk = lane >> 4;                  // 0..3
    const int xorv = (rl & 7) << 4;
    const int aBase0 = (wr * 64 + rl) * 128;       // bytes within A region
    const int bBase0 = (wc * 32 + rl) * 128;       // bytes within B region
    const char* Sb = (const char*)S;

    for (int kt = 0; kt < kTiles; ++kt) {
        asm volatile("s_waitcnt vmcnt(0)" ::: "memory");
        __builtin_amdgcn_s_barrier();
        if (kt + 1 < kTiles) STAGE(kt + 1, ((kt + 1) & 1) * 32768);
        const int bufo = (kt & 1) * 32768;
        #pragma unroll
        for (int ks = 0; ks < 2; ++ks) {
            const int px = (ks * 64 + kchunk * 16) ^ xorv;
            bf16x8 af[4], bfr[2];
            #pragma unroll
            for (int mf = 0; mf < 4; ++mf)
                af[mf] = *(const bf16x8*)(Sb + bufo + aBase0 + mf * 2048 + px);
            #pragma unroll
            for (int nf = 0; nf < 2; ++nf)
                bfr[nf] = *(const bf16x8*)(Sb + bufo + 16384 + bBase0 + nf * 2048 + px);
            #pragma unroll
            for (int mf = 0; mf < 4; ++mf)
                #pragma unroll
                for (int nf = 0; nf < 2; ++nf)
                    acc[mf][nf] = __builtin_amdgcn_mfma_f32_16x16x32_bf16(
                        af[mf], bfr[nf], acc[mf][nf], 0, 0, 0);
        }
    }
#undef STAGE

    u16* Cb = Chm + (size_t)(n0 >> 7) * (MPAD << 7);
    #pragma unroll
    for (int mf = 0; mf < 4; ++mf)
        #pragma unroll
        for (int i = 0; i < 4; ++i) {
            size_t row = m0 + wr * 64 + mf * 16 + (lane >> 4) * 4 + i;
            u16* crow = Cb + row * 128 + wc * 32 + rl;
            #pragma unroll
            for (int nf = 0; nf < 2; ++nf)
                crow[nf * 16] = f32_to_bf16(acc[mf][nf][i]);
        }
}

// ---------------- attention coefficients: a_src/a_dst [10000][10] ----------------
__global__ __launch_bounds__(256) void k_attn(const u16* __restrict__ Hhm,
                                              const float* __restrict__ att_s,
                                              const float* __restrict__ att_d,
                                              float* __restrict__ a_src,
                                              float* __restrict__ a_dst) {
    const int lane = threadIdx.x & 63;
    const int n = blockIdx.x * 4 + (threadIdx.x >> 6);
    if (n >= NN) return;
    const unsigned* Hd = (const unsigned*)Hhm;
    #pragma unroll
    for (int h = 0; h < HEADS; ++h) {
        unsigned pv = Hd[((size_t)h * MPAD + n) * 64 + lane];
        float v0 = bf16lo(pv), v1 = bf16hi(pv);
        int c = h * 128 + lane * 2;
        float s = v0 * att_s[c] + v1 * att_s[c + 1];
        float d = v0 * att_d[c] + v1 * att_d[c + 1];
        #pragma unroll
        for (int o = 32; o; o >>= 1) { s += __shfl_xor(s, o); d += __shfl_xor(d, o); }
        if (lane == 0) { a_src[n * HEADS + h] = s; a_dst[n * HEADS + h] = d; }
    }
}

// ---------------- CSR build ----------------
__global__ void k_count(const int* __restrict__ ei, int* __restrict__ deg) {
    int e = blockIdx.x * blockDim.x + threadIdx.x;
    if (e >= ET) return;
    int d = (e < EE) ? ei[EE + e] : (e - EE);
    atomicAdd(&deg[d], 1);
}

__global__ __launch_bounds__(256) void k_scan(const int* __restrict__ deg,
                                              int* __restrict__ off,
                                              int* __restrict__ cursor) {
    __shared__ int wt[4];
    const int t = threadIdx.x, lane = t & 63, w = t >> 6;
    const int lo = t * 40;
    const int hi = (lo + 40 < NN) ? lo + 40 : NN;
    int s = 0;
    for (int i = lo; i < hi; ++i) s += deg[i];
    int x = s;
    #pragma unroll
    for (int o = 1; o < 64; o <<= 1) { int y = __shfl_up(x, o); if (lane >= o) x += y; }
    if (lane == 63) wt[w] = x;
    __syncthreads();
    int wp = 0;
    for (int k = 0; k < w; ++k) wp += wt[k];
    int run = wp + x - s;
    for (int i = lo; i < hi; ++i) { off[i] = run; cursor[i] = run; run += deg[i]; }
    if (t == 255) off[NN] = wp + x;
}

__global__ void k_scatter(const int* __restrict__ ei, int* __restrict__ cursor,
                          int* __restrict__ csr_src, int* __restrict__ csr_dst) {
    int e = blockIdx.x * blockDim.x + threadIdx.x;
    if (e >= ET) return;
    int s = (e < EE) ? ei[e] : (e - EE);
    int d = (e < EE) ? ei[EE + e] : (e - EE);
    int pos = atomicAdd(&cursor[d], 1);
    csr_src[pos] = s;
    csr_dst[pos] = d;
}

// ---------------- edge weights: wbuf[h][i] = exp(leaky(a_src[s][h]+a_dst[d][h])) ---
__global__ __launch_bounds__(256) void k_edgew(const float* __restrict__ a_src,
                                               const float* __restrict__ a_dst,
                                               const int* __restrict__ csr_s,
                                               const int* __restrict__ csr_d,
                                               float* __restrict__ wbuf) {
    int i = blockIdx.x * 256 + threadIdx.x;
    if (i >= ET) return;
    const int s = csr_s[i], d = csr_d[i];
    const float* ps = a_src + (size_t)s * HEADS;
    const float* pd = a_dst + (size_t)d * HEADS;
    #pragma unroll
    for (int h = 0; h < HEADS; ++h) {
        float e = ps[h] + pd[h];
        e = (e >= 0.f) ? e : 0.2f * e;
        wbuf[(size_t)h * ET + i] = __expf(e);
    }
}

// ---------------- head-split aggregate: wave = (head, 4 nodes) -------------------
template <int LAYER>
__global__ __launch_bounds__(256) void k_agg(const u16* __restrict__ Hhm,
                                             const float* __restrict__ wbuf,
                                             const int* __restrict__ off,
                                             const int* __restrict__ csr,
                                             const float* __restrict__ bias,
                                             unsigned* __restrict__ outp) {
    const int bid = blockIdx.x;
    const int xcd = bid & 7, slot = bid >> 3;
    const int wv = threadIdx.x >> 6, lane = threadIdx.x & 63;
    const int u = slot * 4 + wv;               // [0, 3128)
    if (u >= 3125) return;
    int h, qd;
    if (u < 2500) { h = xcd; qd = u; }
    else {
        int qg = xcd * 625 + (u - 2500);       // [0, 5000)
        h = 8 + (qg >= 2500);
        qd = (qg >= 2500) ? qg - 2500 : qg;
    }
    const int g = lane >> 4, l = lane & 15;
    const int n = qd * 4 + g;
    const int beg = off[n], end = off[n + 1];
    const u16* Hh = Hhm + (size_t)h * (MPAD * 128);
    const float* wp = wbuf + (size_t)h * ET;

    float acc[8] = {};
    float den = 0.f;
    int i = beg;
    for (; i + 1 < end; i += 2) {
        const int s0 = csr[i], s1 = csr[i + 1];
        const float w0 = wp[i], w1 = wp[i + 1];
        const u32x4 v0 = *(const u32x4*)(Hh + (size_t)s0 * 128 + l * 8);
        const u32x4 v1 = *(const u32x4*)(Hh + (size_t)s1 * 128 + l * 8);
        den += w0 + w1;
        #pragma unroll
        for (int j = 0; j < 4; ++j) {
            acc[2 * j]     = fmaf(bf16lo(v0[j]), w0, acc[2 * j]);
            acc[2 * j + 1] = fmaf(bf16hi(v0[j]), w0, acc[2 * j + 1]);
            acc[2 * j]     = fmaf(bf16lo(v1[j]), w1, acc[2 * j]);
            acc[2 * j + 1] = fmaf(bf16hi(v1[j]), w1, acc[2 * j + 1]);
        }
    }
    if (i < end) {
        const int s0 = csr[i];
        const float w0 = wp[i];
        const u32x4 v0 = *(const u32x4*)(Hh + (size_t)s0 * 128 + l * 8);
        den += w0;
        #pragma unroll
        for (int j = 0; j < 4; ++j) {
            acc[2 * j]     = fmaf(bf16lo(v0[j]), w0, acc[2 * j]);
            acc[2 * j + 1] = fmaf(bf16hi(v0[j]), w0, acc[2 * j + 1]);
        }
    }
    const float si = 1.f / (den + 1e-16f);

    u32x4 pk;
    if (LAYER == 1) {
        const int c = h * 128 + l * 8;
        #pragma unroll
        for (int j = 0; j < 4; ++j) {
            float v0 = fmaxf(fmaf(acc[2 * j],     si, bias[c + 2 * j]),     0.f);
            float v1 = fmaxf(fmaf(acc[2 * j + 1], si, bias[c + 2 * j + 1]), 0.f);
            pk[j] = (unsigned)f32_to_bf16(v0) | ((unsigned)f32_to_bf16(v1) << 16);
        }
    } else {
        #pragma unroll
        for (int j = 0; j < 4; ++j) {
            pk[j] = (unsigned)f32_to_bf16(acc[2 * j] * si)
                  | ((unsigned)f32_to_bf16(acc[2 * j + 1] * si) << 16);
        }
    }
    *(u32x4*)(outp + (size_t)h * (MPAD * 64) + (size_t)n * 64 + l * 4) = pk;
}

// zero pad rows NN..MPAD-1 of head-major A2 (10 slices)
__global__ __launch_bounds__(256) void k_zpad(unsigned* __restrict__ A2) {
    int idx = blockIdx.x * 256 + threadIdx.x;       // 10*112*64 = 71680 dwords
    if (idx >= 10 * 112 * 64) return;
    int h = idx / 7168, r = idx - h * 7168;
    int row = NN + (r >> 6), dw = r & 63;
    A2[((size_t)h * MPAD + row) * 64 + dw] = 0u;
}

// final: out[n][c] = relu(0.1 * sum_h Z[h][n][c] + b2[c])
__global__ __launch_bounds__(256) void k_final(const unsigned* __restrict__ Z,
                                               const float* __restrict__ b2,
                                               float* __restrict__ out) {
    int t = blockIdx.x * 256 + threadIdx.x;         // NN*64 dword slots
    if (t >= NN * 64) return;
    int n = t >> 6, d = t & 63;
    float s0 = 0.f, s1 = 0.f;
    #pragma unroll
    for (int h = 0; h < HEADS; ++h) {
        unsigned pv = Z[(size_t)h * (MPAD * 64) + (size_t)n * 64 + d];
        s0 += bf16lo(pv);
        s1 += bf16hi(pv);
    }
    float2 z;
    z.x = fmaxf(fmaf(s0, 0.1f, b2[2 * d]),     0.f);
    z.y = fmaxf(fmaf(s1, 0.1f, b2[2 * d + 1]), 0.f);
    *(float2*)(out + (size_t)n * 128 + 2 * d) = z;
}

// ---------------- host ----------------
extern "C" void kernel_launch(void* const* d_in, const int* in_sizes, int n_in,
                              void* d_out, int out_size, void* d_ws, size_t ws_size,
                              hipStream_t stream) {
    const float* x   = (const float*)d_in[0];
    const int*   ei  = (const int*)  d_in[1];
    const float* W1  = (const float*)d_in[2];
    const float* as1 = (const float*)d_in[3];
    const float* ad1 = (const float*)d_in[4];
    const float* b1  = (const float*)d_in[5];
    const float* W2  = (const float*)d_in[6];
    const float* as2 = (const float*)d_in[7];
    const float* ad2 = (const float*)d_in[8];
    const float* b2  = (const float*)d_in[9];

    char* ws = (char*)d_ws;
    const size_t A1_OFF  = 0;                       // A1 [MPAD][2048] bf16 (41.4MB)
    const size_t A2_OFF  = 0;                       // A2hm / Z [10][MPAD][128] bf16
    const size_t B2T_OFF = (size_t)MPAD * NH * 2;   // 25,886,720 (+3.28MB)
    const size_t WB_OFF  = B2T_OFF + (size_t)NH * NH * 2;   // 29,163,520 (+6.8MB)
    const size_t H_OFF   = (size_t)MPAD * K1PAD * 2;        // 41,418,752
    const size_t B1T_OFF = H_OFF + (size_t)MPAD * NH * 2;   // 67,305,472
    size_t o = B1T_OFF + (size_t)NH * K1PAD * 2;
    const size_t AS_OFF  = o; o += 400128;
    const size_t AD_OFF  = o; o += 400128;
    const size_t DEG_OFF = o; o += 40064;
    const size_t OFF_OFF = o; o += 40064;
    const size_t CUR_OFF = o; o += 40064;
    const size_t CSR_OFF = o; o += 680064;
    const size_t CSD_OFF = o; o += 680064;
    if (ws_size < o) return;

    u16*      A1   = (u16*)(ws + A1_OFF);
    unsigned* A2   = (unsigned*)(ws + A2_OFF);
    u16*      B2t  = (u16*)(ws + B2T_OFF);
    float*    wbuf = (float*)(ws + WB_OFF);
    u16*      H    = (u16*)(ws + H_OFF);
    u16*      B1t  = (u16*)(ws + B1T_OFF);
    float*    aS   = (float*)(ws + AS_OFF);
    float*    aD   = (float*)(ws + AD_OFF);
    int*      deg  = (int*)(ws + DEG_OFF);
    int*      offp = (int*)(ws + OFF_OFF);
    int*      cur  = (int*)(ws + CUR_OFF);
    int*      csr  = (int*)(ws + CSR_OFF);
    int*      csd  = (int*)(ws + CSD_OFF);

    // CSR build
    hipMemsetAsync(deg, 0, NN * sizeof(int), stream);
    k_count<<<(ET + 255) / 256, 256, 0, stream>>>(ei, deg);
    k_scan<<<1, 256, 0, stream>>>(deg, offp, cur);
    k_scatter<<<(ET + 255) / 256, 256, 0, stream>>>(ei, cur, csr, csd);

    // layer 1
    k_conv_x<<<2048, 256, 0, stream>>>(x, (uint2*)A1);
    k_convT<<<dim3(K1PAD / 32, NH / 32), dim3(32, 8), 0, stream>>>(W1, B1t, FIN, NH, K1PAD);
    k_gemm<false><<<NWG, 512, 0, stream>>>(A1, B1t, H, K1PAD, K1PAD / 64);
    k_attn<<<2500, 256, 0, stream>>>(H, as1, ad1, aS, aD);
    k_edgew<<<(ET + 255) / 256, 256, 0, stream>>>(aS, aD, csr, csd, wbuf);
    k_agg<1><<<6256, 256, 0, stream>>>(H, wbuf, offp, csr, b1, A2);
    k_zpad<<<280, 256, 0, stream>>>(A2);

    // layer 2
    k_convT<<<dim3(NH / 32, NH / 32), dim3(32, 8), 0, stream>>>(W2, B2t, NH, NH, NH);
    k_gemm<true><<<NWG, 512, 0, stream>>>((u16*)A2, B2t, H, NH, NH / 64);
    k_attn<<<2500, 256, 0, stream>>>(H, as2, ad2, aS, aD);
    k_edgew<<<(ET + 255) / 256, 256, 0, stream>>>(aS, aD, csr, csd, wbuf);
    k_agg<2><<<6256, 256, 0, stream>>>(H, wbuf, offp, csr, b2, A2);
    k_final<<<(NN * 64 + 255) / 256, 256, 0, stream>>>(A2, b2, (float*)d_out);
}

// Round 11
// 289.381 us; speedup vs baseline: 1.5768x; 1.0487x over previous
//
#include <hip/hip_runtime.h>

typedef unsigned short u16;
typedef __attribute__((ext_vector_type(8))) short bf16x8;
typedef __attribute__((ext_vector_type(4))) float f32x4;
typedef __attribute__((ext_vector_type(4))) unsigned u32x4;

#define NN    10000
#define EE    160000
#define ET    170000      // EE + NN self loops
#define FIN   2000
#define MPAD  10112       // 79*128
#define K1PAD 2048
#define NH    1280        // heads*channels
#define HEADS 10
#define NT    10          // N tiles (1280/128) == heads
#define NWG   790         // 79*10 gemm workgroups

__device__ __forceinline__ u16 f32_to_bf16(float f) {
    unsigned u = __float_as_uint(f);
    unsigned r = (u + 0x7fffu + ((u >> 16) & 1u)) >> 16;
    return (u16)r;
}
__device__ __forceinline__ float bf16lo(unsigned pv) { return __uint_as_float(pv << 16); }
__device__ __forceinline__ float bf16hi(unsigned pv) { return __uint_as_float(pv & 0xffff0000u); }

__device__ __forceinline__ void gload16(const u16* g, u16* l) {
    __builtin_amdgcn_global_load_lds(
        (const __attribute__((address_space(1))) void*)g,
        (__attribute__((address_space(3))) void*)l, 16, 0, 0);
}

// ---------------- prep: conv_x + convT(W1)  (runs BEFORE gemm1) ----------------
// blocks [0,2048): x f32 -> A1 bf16 [MPAD][2048] zero-padded
// blocks [2048,4608): W1 [2000][1280] -> B1t [1280][2048] bf16 (transpose+pad)
__global__ __launch_bounds__(256) void k_prep(const float* __restrict__ x,
                                              uint2* __restrict__ A1,
                                              const float* __restrict__ W1,
                                              u16* __restrict__ B1t) {
    __shared__ float tile[32][33];
    const int bid = blockIdx.x;
    const int t = threadIdx.x;
    if (bid < 2048) {
        const int total = MPAD * (K1PAD / 4);
        for (int idx = bid * 256 + t; idx < total; idx += 2048 * 256) {
            int r = idx >> 9;
            int c = (idx & 511) << 2;
            float4 v = make_float4(0.f, 0.f, 0.f, 0.f);
            if (r < NN && c < FIN) v = *(const float4*)(x + (size_t)r * FIN + c);
            uint2 p;
            p.x = (unsigned)f32_to_bf16(v.x) | ((unsigned)f32_to_bf16(v.y) << 16);
            p.y = (unsigned)f32_to_bf16(v.z) | ((unsigned)f32_to_bf16(v.w) << 16);
            A1[idx] = p;
        }
        return;
    }
    const int tx = t & 31, ty = t >> 5;   // (32, 8)
    int b = bid - 2048;                   // 64 x 40
    int k0 = (b & 63) * 32, n0 = (b >> 6) * 32;
    #pragma unroll
    for (int i = 0; i < 32; i += 8) {
        int k = k0 + ty + i;
        tile[ty + i][tx] = (k < FIN) ? W1[(size_t)k * NH + n0 + tx] : 0.f;
    }
    __syncthreads();
    #pragma unroll
    for (int i = 0; i < 32; i += 8) {
        int n = n0 + ty + i, k = k0 + tx;
        B1t[(size_t)n * K1PAD + k] = f32_to_bf16(tile[tx][ty + i]);
    }
}

// W2 [1280][1280] -> B2t [1280][1280] bf16; must run AFTER gemm1 (B2t aliases A1)
__global__ __launch_bounds__(256) void k_prepW2(const float* __restrict__ W2,
                                                u16* __restrict__ B2t) {
    __shared__ float tile[32][33];
    const int t = threadIdx.x;
    const int tx = t & 31, ty = t >> 5;   // (32, 8)
    int b = blockIdx.x;                   // 40 x 40
    int k0 = (b % 40) * 32, n0 = (b / 40) * 32;
    #pragma unroll
    for (int i = 0; i < 32; i += 8)
        tile[ty + i][tx] = W2[(size_t)(k0 + ty + i) * NH + n0 + tx];
    __syncthreads();
    #pragma unroll
    for (int i = 0; i < 32; i += 8) {
        int n = n0 + ty + i, k = k0 + tx;
        B2t[(size_t)n * NH + k] = f32_to_bf16(tile[tx][ty + i]);
    }
}

// ---------------- GEMM -> head-major C [10][MPAD][128] + fused attn coeffs -----
// 128x128 tile, BK=64, 8 waves (wave tile 64x32), double-buffered 64KB LDS.
// Schedule: wait vmcnt(0) -> barrier -> stage(kt+1) -> 32 MFMA (round-9 proven).
// Epilogue also computes a_src[n][h] = sum_c H[h][n][c]*att_s[h][c] (and a_dst)
// via rl-shfl reduce + LDS atomic across the 4 wc waves.

template <bool AHM>
__global__ __launch_bounds__(512) void k_gemm(const u16* __restrict__ A,
                                              const u16* __restrict__ Bt,
                                              u16* __restrict__ Chm,
                                              const int Kpad, const int kTiles,
                                              const float* __restrict__ att_s,
                                              const float* __restrict__ att_d,
                                              float* __restrict__ a_srcp,
                                              float* __restrict__ a_dstp) {
    __shared__ __attribute__((aligned(16))) u16 S[32768];   // 2 x (A 16KB + B 16KB)
    const int bid = blockIdx.x;
    const int xcd = bid & 7, idx = bid >> 3;
    const int q = NWG >> 3, r = NWG & 7;
    const int L = (xcd < r) ? (xcd * (q + 1) + idx)
                            : (r * (q + 1) + (xcd - r) * q + idx);
    const size_t m0 = (size_t)(L / NT) * 128, n0 = (size_t)(L % NT) * 128;
    const int h = (int)(n0 >> 7);

    const int t = threadIdx.x;
    const int lane = t & 63;
    const int wave = t >> 6;              // 0..7
    const int wr = wave >> 2, wc = wave & 3;

    f32x4 acc[4][2] = {};

    const int srow = t >> 3;
    const int klocal = (((t & 7) ^ ((t >> 3) & 7)) << 3);   // elems within BK=64
    const u16* aRow = AHM ? (A + (m0 + srow) * 128 + klocal)
                          : (A + (m0 + srow) * (size_t)Kpad + klocal);
    const u16* bRow = Bt + (n0 + srow) * (size_t)Kpad + klocal;
    const size_t aStep = AHM ? (size_t)64 * 128 : (size_t)64 * Kpad;
    const size_t bStep = (size_t)64 * Kpad;

#define STAGE(kt_, bufb_) do {                                                   \
        char* db = (char*)S + (bufb_) + wave * 1024;                             \
        const u16* aP;                                                           \
        if (AHM) aP = aRow + (size_t)((kt_) >> 1) * (MPAD << 7) + ((kt_) & 1) * 64; \
        else     aP = aRow + (size_t)(kt_) * 64;                                 \
        const u16* bP = bRow + (size_t)(kt_) * 64;                               \
        gload16(aP,         (u16*)(db));                                         \
        gload16(aP + aStep, (u16*)(db + 8192));                                  \
        gload16(bP,         (u16*)(db + 16384));                                 \
        gload16(bP + bStep, (u16*)(db + 24576));                                 \
    } while (0)

    STAGE(0, 0);

    const int rl = lane & 15;
    const int kchunk = lane >> 4;                  // 0..3
    const int xorv = (rl & 7) << 4;
    const int aBase0 = (wr * 64 + rl) * 128;       // bytes within A region
    const int bBase0 = (wc * 32 + rl) * 128;       // bytes within B region
    const char* Sb = (const char*)S;

    for (int kt = 0; kt < kTiles; ++kt) {
        asm volatile("s_waitcnt vmcnt(0)" ::: "memory");
        __builtin_amdgcn_s_barrier();
        if (kt + 1 < kTiles) STAGE(kt + 1, ((kt + 1) & 1) * 32768);
        const int bufo = (kt & 1) * 32768;
        #pragma unroll
        for (int ks = 0; ks < 2; ++ks) {
            const int px = (ks * 64 + kchunk * 16) ^ xorv;
            bf16x8 af[4], bfr[2];
            #pragma unroll
            for (int mf = 0; mf < 4; ++mf)
                af[mf] = *(const bf16x8*)(Sb + bufo + aBase0 + mf * 2048 + px);
            #pragma unroll
            for (int nf = 0; nf < 2; ++nf)
                bfr[nf] = *(const bf16x8*)(Sb + bufo + 16384 + bBase0 + nf * 2048 + px);
            #pragma unroll
            for (int mf = 0; mf < 4; ++mf)
                #pragma unroll
                for (int nf = 0; nf < 2; ++nf)
                    acc[mf][nf] = __builtin_amdgcn_mfma_f32_16x16x32_bf16(
                        af[mf], bfr[nf], acc[mf][nf], 0, 0, 0);
        }
    }
#undef STAGE

    // ---- repurpose LDS for attention-coefficient reduction ----
    float* red_s = (float*)S;          // [128]
    float* red_d = red_s + 128;        // [128]
    __syncthreads();
    if (t < 128) { red_s[t] = 0.f; red_d[t] = 0.f; }
    __syncthreads();

    // C store (head-major)
    u16* Cb = Chm + (size_t)h * (MPAD << 7);
    #pragma unroll
    for (int mf = 0; mf < 4; ++mf)
        #pragma unroll
        for (int i = 0; i < 4; ++i) {
            size_t row = m0 + wr * 64 + mf * 16 + (lane >> 4) * 4 + i;
            u16* crow = Cb + row * 128 + wc * 32 + rl;
            #pragma unroll
            for (int nf = 0; nf < 2; ++nf)
                crow[nf * 16] = f32_to_bf16(acc[mf][nf][i]);
        }

    // attention partials: cols of this lane = wc*32+rl, wc*32+16+rl
    const float as0 = att_s[h * 128 + wc * 32 + rl];
    const float as1 = att_s[h * 128 + wc * 32 + 16 + rl];
    const float ad0 = att_d[h * 128 + wc * 32 + rl];
    const float ad1 = att_d[h * 128 + wc * 32 + 16 + rl];
    #pragma unroll
    for (int mf = 0; mf < 4; ++mf)
        #pragma unroll
        for (int i = 0; i < 4; ++i) {
            float ps = acc[mf][0][i] * as0 + acc[mf][1][i] * as1;
            float pd = acc[mf][0][i] * ad0 + acc[mf][1][i] * ad1;
            #pragma unroll
            for (int o = 1; o < 16; o <<= 1) {
                ps += __shfl_xor(ps, o);
                pd += __shfl_xor(pd, o);
            }
            if (rl == 0) {
                int rloc = wr * 64 + mf * 16 + (lane >> 4) * 4 + i;
                atomicAdd(&red_s[rloc], ps);
                atomicAdd(&red_d[rloc], pd);
            }
        }
    __syncthreads();
    if (t < 128) {
        size_t nrow = m0 + t;
        if (nrow < NN) {
            a_srcp[nrow * HEADS + h] = red_s[t];
            a_dstp[nrow * HEADS + h] = red_d[t];
        }
    }
}

// ---------------- CSR build ----------------
__global__ void k_count(const int* __restrict__ ei, int* __restrict__ deg) {
    int e = blockIdx.x * blockDim.x + threadIdx.x;
    if (e >= ET) return;
    int d = (e < EE) ? ei[EE + e] : (e - EE);
    atomicAdd(&deg[d], 1);
}

__global__ __launch_bounds__(256) void k_scan(const int* __restrict__ deg,
                                              int* __restrict__ off,
                                              int* __restrict__ cursor) {
    __shared__ int wt[4];
    const int t = threadIdx.x, lane = t & 63, w = t >> 6;
    const int lo = t * 40;
    const int hi = (lo + 40 < NN) ? lo + 40 : NN;
    int s = 0;
    for (int i = lo; i < hi; ++i) s += deg[i];
    int x = s;
    #pragma unroll
    for (int o = 1; o < 64; o <<= 1) { int y = __shfl_up(x, o); if (lane >= o) x += y; }
    if (lane == 63) wt[w] = x;
    __syncthreads();
    int wp = 0;
    for (int k = 0; k < w; ++k) wp += wt[k];
    int run = wp + x - s;
    for (int i = lo; i < hi; ++i) { off[i] = run; cursor[i] = run; run += deg[i]; }
    if (t == 255) off[NN] = wp + x;
}

__global__ void k_scatter(const int* __restrict__ ei, int* __restrict__ cursor,
                          int* __restrict__ csr_src) {
    int e = blockIdx.x * blockDim.x + threadIdx.x;
    if (e >= ET) return;
    int s = (e < EE) ? ei[e] : (e - EE);
    int d = (e < EE) ? ei[EE + e] : (e - EE);
    int pos = atomicAdd(&cursor[d], 1);
    csr_src[pos] = s;
}

// ---------------- head-split aggregate: wave = (head, 4 nodes), inline softmax ---
// 16-lane group g owns node qd*4+g; per edge: load csr -> a_src gather (4B, L2) ->
// leaky+exp -> 256B H gather. den replicated in-group (no cross-lane reduce).
// XCD x pinned to head x (+ 1/8 node slice of heads 8,9): ~3MB L2 working set.
// LAYER 1: A2hm[h][n] = bf16(relu(num*si + b1)); blocks >= 6256 zero A2 pad rows.
// LAYER 2: Z[h][n] = bf16(num*si); k_final sums heads.
template <int LAYER>
__global__ __launch_bounds__(256) void k_agg(const u16* __restrict__ Hhm,
                                             const float* __restrict__ a_src,
                                             const float* __restrict__ a_dst,
                                             const int* __restrict__ off,
                                             const int* __restrict__ csr,
                                             const float* __restrict__ bias,
                                             unsigned* __restrict__ outp) {
    const int bid = blockIdx.x;
    if (LAYER == 1 && bid >= 6256) {     // fused zero-pad of rows NN..MPAD-1
        int idx = (bid - 6256) * 256 + threadIdx.x;   // 71680 dwords
        int hh = idx / 7168, rr = idx - hh * 7168;
        int row = NN + (rr >> 6), dw = rr & 63;
        outp[((size_t)hh * MPAD + row) * 64 + dw] = 0u;
        return;
    }
    const int xcd = bid & 7, slot = bid >> 3;
    const int wv = threadIdx.x >> 6, lane = threadIdx.x & 63;
    const int u = slot * 4 + wv;               // [0, 3128)
    if (u >= 3125) return;
    int h, qd;
    if (u < 2500) { h = xcd; qd = u; }
    else {
        int qg = xcd * 625 + (u - 2500);       // [0, 5000)
        h = 8 + (qg >= 2500);
        qd = (qg >= 2500) ? qg - 2500 : qg;
    }
    const int g = lane >> 4, l = lane & 15;
    const int n = qd * 4 + g;
    const int beg = off[n], end = off[n + 1];
    const u16* Hh = Hhm + (size_t)h * (MPAD * 128);
    const float ad = a_dst[n * HEADS + h];

    float acc[8] = {};
    float den = 0.f;
    int i = beg;
    for (; i + 1 < end; i += 2) {
        const int s0 = csr[i], s1 = csr[i + 1];
        float e0 = a_src[s0 * HEADS + h] + ad; e0 = (e0 >= 0.f) ? e0 : 0.2f * e0;
        float e1 = a_src[s1 * HEADS + h] + ad; e1 = (e1 >= 0.f) ? e1 : 0.2f * e1;
        const float w0 = __expf(e0), w1 = __expf(e1);
        const u32x4 v0 = *(const u32x4*)(Hh + (size_t)s0 * 128 + l * 8);
        const u32x4 v1 = *(const u32x4*)(Hh + (size_t)s1 * 128 + l * 8);
        den += w0 + w1;
        #pragma unroll
        for (int j = 0; j < 4; ++j) {
            acc[2 * j]     = fmaf(bf16lo(v0[j]), w0, acc[2 * j]);
            acc[2 * j + 1] = fmaf(bf16hi(v0[j]), w0, acc[2 * j + 1]);
            acc[2 * j]     = fmaf(bf16lo(v1[j]), w1, acc[2 * j]);
            acc[2 * j + 1] = fmaf(bf16hi(v1[j]), w1, acc[2 * j + 1]);
        }
    }
    if (i < end) {
        const int s0 = csr[i];
        float e0 = a_src[s0 * HEADS + h] + ad; e0 = (e0 >= 0.f) ? e0 : 0.2f * e0;
        const float w0 = __expf(e0);
        const u32x4 v0 = *(const u32x4*)(Hh + (size_t)s0 * 128 + l * 8);
        den += w0;
        #pragma unroll
        for (int j = 0; j < 4; ++j) {
            acc[2 * j]     = fmaf(bf16lo(v0[j]), w0, acc[2 * j]);
            acc[2 * j + 1] = fmaf(bf16hi(v0[j]), w0, acc[2 * j + 1]);
        }
    }
    const float si = 1.f / (den + 1e-16f);

    u32x4 pk;
    if (LAYER == 1) {
        const int c = h * 128 + l * 8;
        #pragma unroll
        for (int j = 0; j < 4; ++j) {
            float v0 = fmaxf(fmaf(acc[2 * j],     si, bias[c + 2 * j]),     0.f);
            float v1 = fmaxf(fmaf(acc[2 * j + 1], si, bias[c + 2 * j + 1]), 0.f);
            pk[j] = (unsigned)f32_to_bf16(v0) | ((unsigned)f32_to_bf16(v1) << 16);
        }
    } else {
        #pragma unroll
        for (int j = 0; j < 4; ++j) {
            pk[j] = (unsigned)f32_to_bf16(acc[2 * j] * si)
                  | ((unsigned)f32_to_bf16(acc[2 * j + 1] * si) << 16);
        }
    }
    *(u32x4*)(outp + (size_t)h * (MPAD * 64) + (size_t)n * 64 + l * 4) = pk;
}

// final: out[n][c] = relu(0.1 * sum_h Z[h][n][c] + b2[c])
__global__ __launch_bounds__(256) void k_final(const unsigned* __restrict__ Z,
                                               const float* __restrict__ b2,
                                               float* __restrict__ out) {
    int t = blockIdx.x * 256 + threadIdx.x;         // NN*64 dword slots
    if (t >= NN * 64) return;
    int n = t >> 6, d = t & 63;
    float s0 = 0.f, s1 = 0.f;
    #pragma unroll
    for (int h = 0; h < HEADS; ++h) {
        unsigned pv = Z[(size_t)h * (MPAD * 64) + (size_t)n * 64 + d];
        s0 += bf16lo(pv);
        s1 += bf16hi(pv);
    }
    float2 z;
    z.x = fmaxf(fmaf(s0, 0.1f, b2[2 * d]),     0.f);
    z.y = fmaxf(fmaf(s1, 0.1f, b2[2 * d + 1]), 0.f);
    *(float2*)(out + (size_t)n * 128 + 2 * d) = z;
}

// ---------------- host ----------------
extern "C" void kernel_launch(void* const* d_in, const int* in_sizes, int n_in,
                              void* d_out, int out_size, void* d_ws, size_t ws_size,
                              hipStream_t stream) {
    const float* x   = (const float*)d_in[0];
    const int*   ei  = (const int*)  d_in[1];
    const float* W1  = (const float*)d_in[2];
    const float* as1 = (const float*)d_in[3];
    const float* ad1 = (const float*)d_in[4];
    const float* b1  = (const float*)d_in[5];
    const float* W2  = (const float*)d_in[6];
    const float* as2 = (const float*)d_in[7];
    const float* ad2 = (const float*)d_in[8];
    const float* b2  = (const float*)d_in[9];

    char* ws = (char*)d_ws;
    const size_t A1_OFF  = 0;                       // A1 [MPAD][2048] bf16 (41.4MB)
    const size_t A2_OFF  = 0;                       // A2hm / Z [10][MPAD][128] bf16
    const size_t B2T_OFF = (size_t)MPAD * NH * 2;   // aliases dead-A1 tail; write AFTER gemm1
    const size_t H_OFF   = (size_t)MPAD * K1PAD * 2;        // 41,418,752
    const size_t B1T_OFF = H_OFF + (size_t)MPAD * NH * 2;   // 67,305,472
    size_t o = B1T_OFF + (size_t)NH * K1PAD * 2;
    const size_t AS_OFF  = o; o += 400128;
    const size_t AD_OFF  = o; o += 400128;
    const size_t DEG_OFF = o; o += 40064;
    const size_t OFF_OFF = o; o += 40064;
    const size_t CUR_OFF = o; o += 40064;
    const size_t CSR_OFF = o; o += 680064;
    if (ws_size < o) return;

    u16*      A1   = (u16*)(ws + A1_OFF);
    unsigned* A2   = (unsigned*)(ws + A2_OFF);
    u16*      B2t  = (u16*)(ws + B2T_OFF);
    u16*      H    = (u16*)(ws + H_OFF);
    u16*      B1t  = (u16*)(ws + B1T_OFF);
    float*    aS   = (float*)(ws + AS_OFF);
    float*    aD   = (float*)(ws + AD_OFF);
    int*      deg  = (int*)(ws + DEG_OFF);
    int*      offp = (int*)(ws + OFF_OFF);
    int*      cur  = (int*)(ws + CUR_OFF);
    int*      csr  = (int*)(ws + CSR_OFF);

    // CSR build
    hipMemsetAsync(deg, 0, NN * sizeof(int), stream);
    k_count<<<(ET + 255) / 256, 256, 0, stream>>>(ei, deg);
    k_scan<<<1, 256, 0, stream>>>(deg, offp, cur);
    k_scatter<<<(ET + 255) / 256, 256, 0, stream>>>(ei, cur, csr);

    // conversions needed by gemm1 (x->A1, W1->B1t)
    k_prep<<<4608, 256, 0, stream>>>(x, (uint2*)A1, W1, B1t);

    // layer 1 (gemm computes H + a_src/a_dst)
    k_gemm<false><<<NWG, 512, 0, stream>>>(A1, B1t, H, K1PAD, K1PAD / 64,
                                           as1, ad1, aS, aD);
    // W2 transpose into the now-dead A1 tail region
    k_prepW2<<<1600, 256, 0, stream>>>(W2, B2t);
    k_agg<1><<<6536, 256, 0, stream>>>(H, aS, aD, offp, csr, b1, A2);

    // layer 2
    k_gemm<true><<<NWG, 512, 0, stream>>>((u16*)A2, B2t, H, NH, NH / 64,
                                          as2, ad2, aS, aD);
    k_agg<2><<<6256, 256, 0, stream>>>(H, aS, aD, offp, csr, b2, A2);
    k_final<<<(NN * 64 + 255) / 256, 256, 0, stream>>>(A2, b2, (float*)d_out);
}